// Round 3
// baseline (450.483 us; speedup 1.0000x reference)
//
#include <hip/hip_runtime.h>

#define BB 2
#define NTOK 21952      // 28^3
#define CC 96
#define WD 784          // 28*28
#define NSR 343         // 7^3
#define NSRP 344        // padded (key 343 = zeros)
#define NPAIR 172
#define NSITE 686       // BB*NSR
#define SCALE 0.25f
#define LN_EPS 1e-5f
#define LNB 4116        // k_lepe logical blocks

typedef _Float16 half_t;
typedef __attribute__((ext_vector_type(2))) _Float16 h2;
typedef __attribute__((ext_vector_type(8))) _Float16 h8;
typedef __attribute__((ext_vector_type(2))) __fp16 fp16x2;
union HU { h8 v; h2 p[4]; };

__device__ __forceinline__ h2 pk2(float a, float b) {
    return __builtin_bit_cast(h2, __builtin_amdgcn_cvt_pkrtz(a, b));
}

// ---------------------------------------------------------------------------
// K0: transpose sr_w [96][6144] -> Wt4[1536][96]; also lepe_conv_w -> cwT[27][96]
// ---------------------------------------------------------------------------
__global__ __launch_bounds__(256) void k_wt(
    const float* __restrict__ w, float4* __restrict__ Wt4,
    const float* __restrict__ cw, float* __restrict__ cwT)
{
    const int id = blockIdx.x * 256 + threadIdx.x;
    if (id < 96 * 1536) {
        const int co = id % 96, kbg = id / 96;
        const float4 v = *(const float4*)(w + (size_t)co * 6144 + 4 * kbg);
        Wt4[(size_t)kbg * 96 + co] = v;
    } else if (id < 96 * 1536 + 27 * 96) {
        const int id2 = id - 96 * 1536;
        const int tap = id2 / 96, c = id2 % 96;
        cwT[tap * 96 + c] = cw[c * 27 + tap];
    }
}

// ---------------------------------------------------------------------------
// K1: P[token][288] = x @ [lepe_lin | q1 | q2 | kv2]^T  (+ lepe bias on 0:96)
// ---------------------------------------------------------------------------
__global__ __launch_bounds__(192) void k_proj(
    const float* __restrict__ x, const float* __restrict__ lepe_w,
    const float* __restrict__ lepe_b, const float* __restrict__ q1_w,
    const float* __restrict__ q2_w, const float* __restrict__ kv2_w,
    float* __restrict__ P)
{
    __shared__ h2 xh[48][68];   // [c-pair][token], row 272B (16B aligned)
    __shared__ h2 wh[48][52];   // [c-pair][j],    row 208B (16B aligned)

    const int base = blockIdx.x * 64;
    const int j0 = blockIdx.y * 48;

    for (int it = threadIdx.x; it < 1536; it += 192) {
        int t = it & 63, cq = it >> 6;           // lanes share cq, walk t
        float4 v = *(const float4*)(x + (size_t)(base + t) * 96 + cq * 4);
        xh[cq * 2 + 0][t] = pk2(v.x, v.y);
        xh[cq * 2 + 1][t] = pk2(v.z, v.w);
    }
    for (int it = threadIdx.x; it < 1152; it += 192) {
        int jl = it % 48, cq = it / 48;          // lanes walk jl
        int jg = j0 + jl;
        const float* wrow;
        if (jg < 96)       wrow = lepe_w + jg * 96;
        else if (jg < 144) wrow = q1_w + (jg - 96) * 96;
        else if (jg < 192) wrow = q2_w + (jg - 144) * 96;
        else               wrow = kv2_w + (jg - 192) * 96;
        float4 v = *(const float4*)(wrow + cq * 4);
        wh[cq * 2 + 0][jl] = pk2(v.x, v.y);
        wh[cq * 2 + 1][jl] = pk2(v.z, v.w);
    }
    __syncthreads();

    const int tq = threadIdx.x & 15;
    const int jq = threadIdx.x >> 4;
    float acc[4][4];
#pragma unroll
    for (int i = 0; i < 4; i++)
#pragma unroll
        for (int jj = 0; jj < 4; jj++) acc[i][jj] = 0.f;

    for (int cp = 0; cp < 48; cp++) {
        HU xv, wv;
        xv.v = *(const h8*)(&xh[cp][tq * 4]);
        wv.v = *(const h8*)(&wh[cp][jq * 4]);
#pragma unroll
        for (int i = 0; i < 4; i++)
#pragma unroll
            for (int jj = 0; jj < 4; jj++)
                acc[i][jj] = __builtin_amdgcn_fdot2(xv.p[i], wv.p[jj], acc[i][jj], false);
    }

    float bias[4];
#pragma unroll
    for (int jj = 0; jj < 4; jj++) {
        int jg = j0 + jq * 4 + jj;
        bias[jj] = (jg < 96) ? lepe_b[jg] : 0.f;
    }
#pragma unroll
    for (int i = 0; i < 4; i++) {
        int t = base + tq * 4 + i;
        float4 o = make_float4(acc[i][0] + bias[0], acc[i][1] + bias[1],
                               acc[i][2] + bias[2], acc[i][3] + bias[3]);
        *(float4*)(P + (size_t)t * 288 + j0 + jq * 4) = o;
    }
}

// ---------------------------------------------------------------------------
// K2a: SR conv split-K GEMM. grid (86 site-groups x 16 k-splits), block 128.
// ---------------------------------------------------------------------------
__global__ __launch_bounds__(128) void k_sr_a(
    const float* __restrict__ x, const float4* __restrict__ Wt4,
    float* __restrict__ pa)
{
    __shared__ float patch[8 * 384];
    const int sg = blockIdx.x, ks = blockIdx.y;
    const int ci0 = ks * 6;

    for (int pr = threadIdx.x; pr < 512; pr += 128) {
        int s = pr >> 6, p = pr & 63;
        int s_g = sg * 8 + s; if (s_g > NSITE - 1) s_g = NSITE - 1;
        int b = s_g / NSR, sloc = s_g % NSR;
        int si = sloc / 49, sj = (sloc / 7) % 7, sk = sloc % 7;
        int a = p >> 4, q = (p >> 2) & 3, r = p & 3;
        int n = (4 * si + a) * WD + (4 * sj + q) * 28 + (4 * sk + r);
        const float2* xp = (const float2*)(x + ((size_t)b * NTOK + n) * 96 + ci0);
        float2 v0 = xp[0], v1 = xp[1], v2 = xp[2];
        int base = s * 384 + p;
        patch[base +   0] = v0.x; patch[base +  64] = v0.y;
        patch[base + 128] = v1.x; patch[base + 192] = v1.y;
        patch[base + 256] = v2.x; patch[base + 320] = v2.y;
    }
    __syncthreads();

    const int co = threadIdx.x;
    if (co >= 96) return;
    float acc[8];
#pragma unroll
    for (int s = 0; s < 8; s++) acc[s] = 0.f;
    const float4* p4 = (const float4*)patch;
    const float4* wb = Wt4 + (size_t)ks * 96 * 96 + co;
    for (int kb = 0; kb < 96; kb++) {
        float4 w = wb[(size_t)kb * 96];
#pragma unroll
        for (int s = 0; s < 8; s++) {
            float4 pv = p4[s * 96 + kb];
            acc[s] += pv.x * w.x + pv.y * w.y + pv.z * w.z + pv.w * w.w;
        }
    }
#pragma unroll
    for (int s = 0; s < 8; s++) {
        int s_g = sg * 8 + s;
        if (s_g < NSITE)
            pa[((size_t)s_g * 16 + ks) * 96 + co] = acc[s];
    }
}

// ---------------------------------------------------------------------------
// K2b: reduce 16 partials + bias + LN + GELU + kv1 -> k1/v1 [B][3][343][16]
// ---------------------------------------------------------------------------
__global__ __launch_bounds__(96) void k_sr_b(
    const float* __restrict__ pa, const float* __restrict__ sr_b,
    const float* __restrict__ norm_g, const float* __restrict__ norm_b,
    const float* __restrict__ kv1_w, float* __restrict__ k1,
    float* __restrict__ v1)
{
    __shared__ float xs_s[96];
    __shared__ float gx[96];
    const int s_g = blockIdx.x;
    const int b = s_g / NSR, s = s_g % NSR;
    const int co = threadIdx.x;

    const float* pp = pa + (size_t)s_g * 16 * 96 + co;
    float acc = sr_b[co];
#pragma unroll
    for (int ks = 0; ks < 16; ks++) acc += pp[ks * 96];
    xs_s[co] = acc;
    __syncthreads();

    float m = 0.f, m2 = 0.f;
    for (int c = 0; c < 96; c++) { float v = xs_s[c]; m += v; m2 += v * v; }
    m *= (1.f / 96.f);
    float var = m2 * (1.f / 96.f) - m * m;
    float t = (acc - m) * rsqrtf(var + LN_EPS) * norm_g[co] + norm_b[co];
    gx[co] = 0.5f * t * (1.f + erff(t * 0.70710678118654752f));
    __syncthreads();

    const float4* w4 = (const float4*)(kv1_w + co * 96);
    const float4* g4 = (const float4*)gx;
    float a2 = 0.f;
#pragma unroll
    for (int c = 0; c < 24; c++) {
        float4 w = w4[c]; float4 g = g4[c];
        a2 += g.x * w.x + g.y * w.y + g.z * w.z + g.w * w.w;
    }
    int pair = co / 48, h = (co % 48) / 16, e = co % 16;
    float* dst = pair ? v1 : k1;
    dst[(((size_t)b * 3 + h) * NSR + s) * 16 + e] = a2;
}

// ---------------------------------------------------------------------------
// helpers
// ---------------------------------------------------------------------------
__device__ __forceinline__ void ld16_g(const float* p, float* o) {
    const float4* p4 = (const float4*)p;
#pragma unroll
    for (int i = 0; i < 4; i++) {
        float4 v = p4[i];
        o[4 * i] = v.x; o[4 * i + 1] = v.y; o[4 * i + 2] = v.z; o[4 * i + 3] = v.w;
    }
}
__device__ __forceinline__ void st16_g(float* p, const float* o, float scl) {
    float4* p4 = (float4*)p;
#pragma unroll
    for (int i = 0; i < 4; i++)
        p4[i] = make_float4(o[4 * i] * scl, o[4 * i + 1] * scl,
                            o[4 * i + 2] * scl, o[4 * i + 3] * scl);
}
// q -> f16 with SCALE folded in
__device__ __forceinline__ void cvt_qs(const float* qa, h2* qh) {
#pragma unroll
    for (int i = 0; i < 8; i++)
        qh[i] = pk2(qa[2 * i] * SCALE, qa[2 * i + 1] * SCALE);
}
// K row (2 float4 = 8 elems) -> 4 h2 at kl2[4*idx..]
__device__ __forceinline__ void stage_k(h2* kl2, const float4 kv, int idx) {
    kl2[2 * idx]     = pk2(kv.x, kv.y);
    kl2[2 * idx + 1] = pk2(kv.z, kv.w);
}
// pack pair-interleaved V
__device__ __forceinline__ h8 packV(const float4 A, const float4 B) {
    HU u;
    u.p[0] = pk2(A.x, B.x);
    u.p[1] = pk2(A.y, B.y);
    u.p[2] = pk2(A.z, B.z);
    u.p[3] = pk2(A.w, B.w);
    return u.v;
}

// ---------------------------------------------------------------------------
// 4-query paired attention core. One K/V pair read from LDS (8 x b128) feeds
// FOUR queries' QK and PV -> LDS return bytes per query-key cut 4x vs Q=1.
// This targets the measured LDS-return-bandwidth bound (broadcast reads).
// ---------------------------------------------------------------------------
__device__ __forceinline__ void attn_runp4(
    const h2* kl2, const h2* vp2, int pr0, int pr1,
    const h2 (&qh)[4][8], float (&a)[4][16], float (&l)[4])
{
    const h8* kp = (const h8*)kl2;
    const h8* vp = (const h8*)vp2;
    for (int pr = pr0; pr < pr1; pr++) {
        HU k0, k1, k2, k3, w0, w1, w2, w3;
        k0.v = kp[4 * pr];     k1.v = kp[4 * pr + 1];
        k2.v = kp[4 * pr + 2]; k3.v = kp[4 * pr + 3];
        w0.v = vp[4 * pr];     w1.v = vp[4 * pr + 1];
        w2.v = vp[4 * pr + 2]; w3.v = vp[4 * pr + 3];
#pragma unroll
        for (int j = 0; j < 4; j++) {
            float sa = 0.f, sb = 0.f, ta = 0.f, tb = 0.f;
#pragma unroll
            for (int i = 0; i < 4; i++) {
                sa = __builtin_amdgcn_fdot2(qh[j][i],     k0.p[i], sa, false);
                sb = __builtin_amdgcn_fdot2(qh[j][4 + i], k1.p[i], sb, false);
                ta = __builtin_amdgcn_fdot2(qh[j][i],     k2.p[i], ta, false);
                tb = __builtin_amdgcn_fdot2(qh[j][4 + i], k3.p[i], tb, false);
            }
            float p0 = __expf(sa + sb), p1 = __expf(ta + tb);
            l[j] += p0 + p1;
            h2 pp = pk2(p0, p1);
#pragma unroll
            for (int i = 0; i < 4; i++) {
                a[j][i]      = __builtin_amdgcn_fdot2(pp, w0.p[i], a[j][i],      false);
                a[j][4 + i]  = __builtin_amdgcn_fdot2(pp, w1.p[i], a[j][4 + i],  false);
                a[j][8 + i]  = __builtin_amdgcn_fdot2(pp, w2.p[i], a[j][8 + i],  false);
                a[j][12 + i] = __builtin_amdgcn_fdot2(pp, w3.p[i], a[j][12 + i], false);
            }
        }
    }
}

// ---------------------------------------------------------------------------
// K3: branch-1 SR attention -> y[:, :, 0:48]
// Q=4 per thread, key-split S=2 (khalf = wave, wave-aligned). Block 128.
// 256 queries/block, grid 6 x 86 = 516 blocks (2.02/CU).
// pl merge buffer (64 x 69 floats, stride 69 -> conflict-free) aliased over
// kl2/vp2 via union; extra sync makes aliasing legal.
// ---------------------------------------------------------------------------
__global__ __launch_bounds__(128) void k_attn1(
    const float* __restrict__ P, const float* __restrict__ k1,
    const float* __restrict__ v1, float* __restrict__ y)
{
    __shared__ union U1 {
        struct { h2 kl2[NSRP * 8]; h2 vp2[NPAIR * 16]; } s;
        float pl[64][69];
    } u;
    const int bh = blockIdx.x;
    const int b = bh / 3, h = bh % 3;
    const float4* ks = (const float4*)(k1 + (size_t)bh * NSR * 16);
    const float4* vs = (const float4*)(v1 + (size_t)bh * NSR * 16);
    const float4 z4 = make_float4(0.f, 0.f, 0.f, 0.f);

    for (int idx = threadIdx.x; idx < NSRP * 4; idx += 128) {
        int m = idx >> 2;
        stage_k(u.s.kl2, (m < NSR) ? ks[idx] : z4, idx);
    }
    for (int idx = threadIdx.x; idx < NPAIR * 2; idx += 128) {
        int pr = idx >> 1, hf = idx & 1;
        int ma = 2 * pr, mb = ma + 1;
        float4 a0 = vs[ma * 4 + hf * 2], a1 = vs[ma * 4 + hf * 2 + 1];
        float4 b0 = z4, b1 = z4;
        if (mb < NSR) { b0 = vs[mb * 4 + hf * 2]; b1 = vs[mb * 4 + hf * 2 + 1]; }
        h8* vph = (h8*)u.s.vp2;
        vph[pr * 4 + hf * 2]     = packV(a0, b0);
        vph[pr * 4 + hf * 2 + 1] = packV(a1, b1);
    }
    __syncthreads();

    const int khalf = threadIdx.x >> 6;         // wave-aligned key split
    const int qloc = threadIdx.x & 63;
    const int qbase = blockIdx.y * 256 + qloc;

    bool ok[4]; int nq[4];
#pragma unroll
    for (int j = 0; j < 4; j++) {
        int n = qbase + 64 * j;
        ok[j] = (n < NTOK);
        nq[j] = ok[j] ? n : 0;
    }

    h2 qh[4][8];
#pragma unroll
    for (int j = 0; j < 4; j++) {
        float qa[16];
        ld16_g(P + ((size_t)b * NTOK + nq[j]) * 288 + 96 + h * 16, qa);
        cvt_qs(qa, qh[j]);
    }

    float a[4][16];
#pragma unroll
    for (int j = 0; j < 4; j++)
#pragma unroll
        for (int e = 0; e < 16; e++) a[j][e] = 0.f;
    float l4[4] = {0.f, 0.f, 0.f, 0.f};

    attn_runp4(u.s.kl2, u.s.vp2, khalf ? 86 : 0, khalf ? NPAIR : 86, qh, a, l4);
    if (khalf) {
#pragma unroll
        for (int j = 0; j < 4; j++) l4[j] -= 1.f;   // pad key 343
    }

    __syncthreads();        // all kl2/vp2 reads done before pl overwrites them
    if (khalf) {
#pragma unroll
        for (int j = 0; j < 4; j++) {
#pragma unroll
            for (int e = 0; e < 16; e++) u.pl[qloc][j * 17 + e] = a[j][e];
            u.pl[qloc][j * 17 + 16] = l4[j];
        }
    }
    __syncthreads();
    if (!khalf) {
#pragma unroll
        for (int j = 0; j < 4; j++) {
            if (!ok[j]) continue;
            float l = l4[j] + u.pl[qloc][j * 17 + 16];
            float o[16];
#pragma unroll
            for (int e = 0; e < 16; e++) o[e] = a[j][e] + u.pl[qloc][j * 17 + e];
            st16_g(y + ((size_t)b * NTOK + nq[j]) * 96 + h * 16, o, 1.f / l);
        }
    }
}

// ---------------------------------------------------------------------------
// K4: branch-2 windowed attention -> y[:, :, 48:96]
// Q=4 per thread, NO key/query split: each thread walks all 172 pairs for its
// 4 queries (q = qloc + 86*j). Block 128 (86 active qthreads), 384 blocks.
// No merge buffer, no extra syncs.
// ---------------------------------------------------------------------------
__global__ __launch_bounds__(128) void k_attn2(
    const float* __restrict__ P, float* __restrict__ y)
{
    __shared__ struct { h2 kl2[NSRP * 8]; h2 vp2[NPAIR * 16]; } s;
    const int pb = blockIdx.x;
    const int b = pb / 192;
    const int rem = pb % 192;
    const int h = rem / 64, win = rem % 64;
    const int wh = win >> 4, ww = (win >> 2) & 3, wd = win & 3;
    const int h0 = wh * 7, w0 = ww * 7, d0 = wd * 7;
    const float4 z4 = make_float4(0.f, 0.f, 0.f, 0.f);

    for (int idx = threadIdx.x; idx < NSRP * 4; idx += 128) {
        int m = idx >> 2, e4 = idx & 3;
        float4 kv = z4;
        if (m < NSR) {
            int a = m / 49, bw = (m / 7) % 7, cw = m % 7;
            int n = (h0 + a) * WD + (w0 + bw) * 28 + (d0 + cw);
            kv = *(const float4*)(P + ((size_t)b * NTOK + n) * 288 + 192 + h * 16 + e4 * 4);
        }
        stage_k(s.kl2, kv, idx);
    }
    for (int idx = threadIdx.x; idx < NPAIR * 2; idx += 128) {
        int pr = idx >> 1, hf = idx & 1;
        int ma = 2 * pr, mb = ma + 1;
        int aa = ma / 49, ab = (ma / 7) % 7, ac = ma % 7;
        int na = (h0 + aa) * WD + (w0 + ab) * 28 + (d0 + ac);
        const float* sa = P + ((size_t)b * NTOK + na) * 288 + 240 + h * 16 + hf * 8;
        float4 a0 = *(const float4*)sa, a1 = *(const float4*)(sa + 4);
        float4 b0 = z4, b1 = z4;
        if (mb < NSR) {
            int ba = mb / 49, bbw = (mb / 7) % 7, bc = mb % 7;
            int nb = (h0 + ba) * WD + (w0 + bbw) * 28 + (d0 + bc);
            const float* sb = P + ((size_t)b * NTOK + nb) * 288 + 240 + h * 16 + hf * 8;
            b0 = *(const float4*)sb; b1 = *(const float4*)(sb + 4);
        }
        h8* vph = (h8*)s.vp2;
        vph[pr * 4 + hf * 2]     = packV(a0, b0);
        vph[pr * 4 + hf * 2 + 1] = packV(a1, b1);
    }
    __syncthreads();

    const int qloc = threadIdx.x;
    const bool act = (qloc < 86);

    bool ok[4]; int q[4], n0[4];
#pragma unroll
    for (int j = 0; j < 4; j++) {
        int qq = qloc + 86 * j;
        ok[j] = act && (qq < NSR);
        q[j] = ok[j] ? qq : 0;
        int ai = q[j] / 49, bi = (q[j] / 7) % 7, ci = q[j] % 7;
        n0[j] = (h0 + ai) * WD + (w0 + bi) * 28 + (d0 + ci);
    }

    h2 qh[4][8];
#pragma unroll
    for (int j = 0; j < 4; j++) {
        float qa[16];
        ld16_g(P + ((size_t)b * NTOK + n0[j]) * 288 + 144 + h * 16, qa);
        cvt_qs(qa, qh[j]);
    }

    float a[4][16];
#pragma unroll
    for (int j = 0; j < 4; j++)
#pragma unroll
        for (int e = 0; e < 16; e++) a[j][e] = 0.f;
    float l4[4] = {0.f, 0.f, 0.f, 0.f};

    attn_runp4(s.kl2, s.vp2, 0, NPAIR, qh, a, l4);

#pragma unroll
    for (int j = 0; j < 4; j++) {
        if (!ok[j]) continue;
        float l = l4[j] - 1.f;      // pad key 343: p=exp(0)=1, V=0
        st16_g(y + ((size_t)b * NTOK + n0[j]) * 96 + 48 + h * 16, a[j], 1.f / l);
    }
}

// ---------------------------------------------------------------------------
// K5: LePE depthwise 3x3x3 conv over t = P[:,0:96]; y += lepe
// ---------------------------------------------------------------------------
__global__ __launch_bounds__(256) void k_lepe(
    const float* __restrict__ P, const float* __restrict__ cwT,
    const float* __restrict__ cb, float* __restrict__ y)
{
    const int p = blockIdx.x;
    const int l = (p & 7) * 515 + (p >> 3);
    if (l >= LNB) return;
    const int id = l * 256 + threadIdx.x;
    const int g4 = (id % 24) * 4;
    const int nl = id / 24;
    const int n = nl % NTOK;
    const int h = n / WD, w = (n / 28) % 28, d = n % 28;
    const float* Pb = P + (size_t)(nl - n) * 288;

    float4 acc = *(const float4*)(cb + g4);
#pragma unroll
    for (int tap = 0; tap < 27; tap++) {
        const int dh = tap / 9 - 1, dw = (tap / 3) % 3 - 1, dd = tap % 3 - 1;
        const int hh = h + dh, ww = w + dw, d2 = d + dd;
        const bool v = ((unsigned)hh < 28u) & ((unsigned)ww < 28u) & ((unsigned)d2 < 28u);
        const int nn = v ? (hh * WD + ww * 28 + d2) : n;
        const float m = v ? 1.f : 0.f;
        float4 pv = *(const float4*)(Pb + (size_t)nn * 288 + g4);
        float4 wv = *(const float4*)(cwT + tap * 96 + g4);
        acc.x += pv.x * (wv.x * m);
        acc.y += pv.y * (wv.y * m);
        acc.z += pv.z * (wv.z * m);
        acc.w += pv.w * (wv.w * m);
    }
    float4* yp = (float4*)(y + (size_t)nl * 96 + g4);
    float4 cur = *yp;
    cur.x += acc.x; cur.y += acc.y; cur.z += acc.z; cur.w += acc.w;
    *yp = cur;
}

// ---------------------------------------------------------------------------
// K6: out = y @ proj_w^T + proj_b  — packed-f16 fdot2 GEMM, 64 tok x 48 j tile
// ---------------------------------------------------------------------------
__global__ __launch_bounds__(192) void k_out(
    const float* __restrict__ y, const float* __restrict__ proj_w,
    const float* __restrict__ proj_b, float* __restrict__ out)
{
    __shared__ h2 xh[48][68];
    __shared__ h2 wh[48][52];

    const int base = blockIdx.x * 64;
    const int j0 = blockIdx.y * 48;

    for (int it = threadIdx.x; it < 1536; it += 192) {
        int t = it & 63, cq = it >> 6;
        float4 v = *(const float4*)(y + (size_t)(base + t) * 96 + cq * 4);
        xh[cq * 2 + 0][t] = pk2(v.x, v.y);
        xh[cq * 2 + 1][t] = pk2(v.z, v.w);
    }
    for (int it = threadIdx.x; it < 1152; it += 192) {
        int jl = it % 48, cq = it / 48;
        float4 v = *(const float4*)(proj_w + (size_t)(j0 + jl) * 96 + cq * 4);
        wh[cq * 2 + 0][jl] = pk2(v.x, v.y);
        wh[cq * 2 + 1][jl] = pk2(v.z, v.w);
    }
    __syncthreads();

    const int tq = threadIdx.x & 15;
    const int jq = threadIdx.x >> 4;
    float acc[4][4];
#pragma unroll
    for (int i = 0; i < 4; i++)
#pragma unroll
        for (int jj = 0; jj < 4; jj++) acc[i][jj] = 0.f;

    for (int cp = 0; cp < 48; cp++) {
        HU xv, wv;
        xv.v = *(const h8*)(&xh[cp][tq * 4]);
        wv.v = *(const h8*)(&wh[cp][jq * 4]);
#pragma unroll
        for (int i = 0; i < 4; i++)
#pragma unroll
            for (int jj = 0; jj < 4; jj++)
                acc[i][jj] = __builtin_amdgcn_fdot2(xv.p[i], wv.p[jj], acc[i][jj], false);
    }

    float4 bias = *(const float4*)(proj_b + j0 + jq * 4);
#pragma unroll
    for (int i = 0; i < 4; i++) {
        int t = base + tq * 4 + i;
        float4 o = make_float4(acc[i][0] + bias.x, acc[i][1] + bias.y,
                               acc[i][2] + bias.z, acc[i][3] + bias.w);
        *(float4*)(out + (size_t)t * 96 + j0 + jq * 4) = o;
    }
}

extern "C" void kernel_launch(void* const* d_in, const int* in_sizes, int n_in,
                              void* d_out, int out_size, void* d_ws, size_t ws_size,
                              hipStream_t stream) {
    const float* x          = (const float*)d_in[0];
    const float* lepe_lin_w = (const float*)d_in[4];
    const float* lepe_lin_b = (const float*)d_in[5];
    const float* lepe_conv_w= (const float*)d_in[6];
    const float* lepe_conv_b= (const float*)d_in[7];
    const float* sr_w       = (const float*)d_in[8];
    const float* sr_b       = (const float*)d_in[9];
    const float* norm_g     = (const float*)d_in[10];
    const float* norm_b     = (const float*)d_in[11];
    const float* q1_w       = (const float*)d_in[12];
    const float* kv1_w      = (const float*)d_in[13];
    const float* q2_w       = (const float*)d_in[14];
    const float* kv2_w      = (const float*)d_in[15];
    const float* proj_w     = (const float*)d_in[16];
    const float* proj_b     = (const float*)d_in[17];

    float* P   = (float*)d_ws;                        // [B*N][288]
    float* k1  = P + (size_t)BB * NTOK * 288;         // [B][3][343][16]
    float* v1  = k1 + (size_t)BB * 3 * NSR * 16;
    float* y   = v1 + (size_t)BB * 3 * NSR * 16;      // [B*N][96]
    float* pa  = y + (size_t)BB * NTOK * 96;          // [686][16][96]
    float* Wt  = pa + (size_t)NSITE * 16 * 96;        // [1536][96] float4
    float* cwT = Wt + (size_t)1536 * 96 * 4;          // [27][96]

    k_wt<<<587, 256, 0, stream>>>(sr_w, (float4*)Wt, lepe_conv_w, cwT);
    k_proj<<<dim3(686, 6), 192, 0, stream>>>(x, lepe_lin_w, lepe_lin_b, q1_w, q2_w, kv2_w, P);
    k_sr_a<<<dim3(86, 16), 128, 0, stream>>>(x, (const float4*)Wt, pa);
    k_sr_b<<<NSITE, 96, 0, stream>>>(pa, sr_b, norm_g, norm_b, kv1_w, k1, v1);
    k_attn1<<<dim3(6, 86), 128, 0, stream>>>(P, k1, v1, y);
    k_attn2<<<384, 128, 0, stream>>>(P, y);
    k_lepe<<<4120, 256, 0, stream>>>(P, cwT, lepe_conv_b, y);
    k_out<<<dim3(686, 2), 192, 0, stream>>>(y, proj_w, proj_b, (float*)d_out);
}

// Round 4
// 372.734 us; speedup vs baseline: 1.2086x; 1.2086x over previous
//
#include <hip/hip_runtime.h>

#define BB 2
#define NTOK 21952      // 28^3
#define CC 96
#define WD 784          // 28*28
#define NSR 343         // 7^3
#define NSRP 344        // padded (key 343 = zeros)
#define NPAIR 172
#define NSITE 686       // BB*NSR
#define SCALE 0.25f
#define LN_EPS 1e-5f
#define LNB 4116        // k_lepe logical blocks

typedef _Float16 half_t;
typedef __attribute__((ext_vector_type(2))) _Float16 h2;
typedef __attribute__((ext_vector_type(8))) _Float16 h8;
typedef __attribute__((ext_vector_type(2))) __fp16 fp16x2;
union HU { h8 v; h2 p[4]; };

__device__ __forceinline__ h2 pk2(float a, float b) {
    return __builtin_bit_cast(h2, __builtin_amdgcn_cvt_pkrtz(a, b));
}

// ---------------------------------------------------------------------------
// K0: transpose sr_w [96][6144] -> Wt4[1536][96]; also lepe_conv_w -> cwT[27][96]
// ---------------------------------------------------------------------------
__global__ __launch_bounds__(256) void k_wt(
    const float* __restrict__ w, float4* __restrict__ Wt4,
    const float* __restrict__ cw, float* __restrict__ cwT)
{
    const int id = blockIdx.x * 256 + threadIdx.x;
    if (id < 96 * 1536) {
        const int co = id % 96, kbg = id / 96;
        const float4 v = *(const float4*)(w + (size_t)co * 6144 + 4 * kbg);
        Wt4[(size_t)kbg * 96 + co] = v;
    } else if (id < 96 * 1536 + 27 * 96) {
        const int id2 = id - 96 * 1536;
        const int tap = id2 / 96, c = id2 % 96;
        cwT[tap * 96 + c] = cw[c * 27 + tap];
    }
}

// ---------------------------------------------------------------------------
// K1: P[token][288] = x @ [lepe_lin | q1 | q2 | kv2]^T  (+ lepe bias on 0:96)
// ---------------------------------------------------------------------------
__global__ __launch_bounds__(192) void k_proj(
    const float* __restrict__ x, const float* __restrict__ lepe_w,
    const float* __restrict__ lepe_b, const float* __restrict__ q1_w,
    const float* __restrict__ q2_w, const float* __restrict__ kv2_w,
    float* __restrict__ P)
{
    __shared__ h2 xh[48][68];   // [c-pair][token], row 272B (16B aligned)
    __shared__ h2 wh[48][52];   // [c-pair][j],    row 208B (16B aligned)

    const int base = blockIdx.x * 64;
    const int j0 = blockIdx.y * 48;

    for (int it = threadIdx.x; it < 1536; it += 192) {
        int t = it & 63, cq = it >> 6;           // lanes share cq, walk t
        float4 v = *(const float4*)(x + (size_t)(base + t) * 96 + cq * 4);
        xh[cq * 2 + 0][t] = pk2(v.x, v.y);
        xh[cq * 2 + 1][t] = pk2(v.z, v.w);
    }
    for (int it = threadIdx.x; it < 1152; it += 192) {
        int jl = it % 48, cq = it / 48;          // lanes walk jl
        int jg = j0 + jl;
        const float* wrow;
        if (jg < 96)       wrow = lepe_w + jg * 96;
        else if (jg < 144) wrow = q1_w + (jg - 96) * 96;
        else if (jg < 192) wrow = q2_w + (jg - 144) * 96;
        else               wrow = kv2_w + (jg - 192) * 96;
        float4 v = *(const float4*)(wrow + cq * 4);
        wh[cq * 2 + 0][jl] = pk2(v.x, v.y);
        wh[cq * 2 + 1][jl] = pk2(v.z, v.w);
    }
    __syncthreads();

    const int tq = threadIdx.x & 15;
    const int jq = threadIdx.x >> 4;
    float acc[4][4];
#pragma unroll
    for (int i = 0; i < 4; i++)
#pragma unroll
        for (int jj = 0; jj < 4; jj++) acc[i][jj] = 0.f;

    for (int cp = 0; cp < 48; cp++) {
        HU xv, wv;
        xv.v = *(const h8*)(&xh[cp][tq * 4]);
        wv.v = *(const h8*)(&wh[cp][jq * 4]);
#pragma unroll
        for (int i = 0; i < 4; i++)
#pragma unroll
            for (int jj = 0; jj < 4; jj++)
                acc[i][jj] = __builtin_amdgcn_fdot2(xv.p[i], wv.p[jj], acc[i][jj], false);
    }

    float bias[4];
#pragma unroll
    for (int jj = 0; jj < 4; jj++) {
        int jg = j0 + jq * 4 + jj;
        bias[jj] = (jg < 96) ? lepe_b[jg] : 0.f;
    }
#pragma unroll
    for (int i = 0; i < 4; i++) {
        int t = base + tq * 4 + i;
        float4 o = make_float4(acc[i][0] + bias[0], acc[i][1] + bias[1],
                               acc[i][2] + bias[2], acc[i][3] + bias[3]);
        *(float4*)(P + (size_t)t * 288 + j0 + jq * 4) = o;
    }
}

// ---------------------------------------------------------------------------
// K2a: SR conv split-K GEMM. grid (86 site-groups x 16 k-splits), block 128.
// ---------------------------------------------------------------------------
__global__ __launch_bounds__(128) void k_sr_a(
    const float* __restrict__ x, const float4* __restrict__ Wt4,
    float* __restrict__ pa)
{
    __shared__ float patch[8 * 384];
    const int sg = blockIdx.x, ks = blockIdx.y;
    const int ci0 = ks * 6;

    for (int pr = threadIdx.x; pr < 512; pr += 128) {
        int s = pr >> 6, p = pr & 63;
        int s_g = sg * 8 + s; if (s_g > NSITE - 1) s_g = NSITE - 1;
        int b = s_g / NSR, sloc = s_g % NSR;
        int si = sloc / 49, sj = (sloc / 7) % 7, sk = sloc % 7;
        int a = p >> 4, q = (p >> 2) & 3, r = p & 3;
        int n = (4 * si + a) * WD + (4 * sj + q) * 28 + (4 * sk + r);
        const float2* xp = (const float2*)(x + ((size_t)b * NTOK + n) * 96 + ci0);
        float2 v0 = xp[0], v1 = xp[1], v2 = xp[2];
        int base = s * 384 + p;
        patch[base +   0] = v0.x; patch[base +  64] = v0.y;
        patch[base + 128] = v1.x; patch[base + 192] = v1.y;
        patch[base + 256] = v2.x; patch[base + 320] = v2.y;
    }
    __syncthreads();

    const int co = threadIdx.x;
    if (co >= 96) return;
    float acc[8];
#pragma unroll
    for (int s = 0; s < 8; s++) acc[s] = 0.f;
    const float4* p4 = (const float4*)patch;
    const float4* wb = Wt4 + (size_t)ks * 96 * 96 + co;
    for (int kb = 0; kb < 96; kb++) {
        float4 w = wb[(size_t)kb * 96];
#pragma unroll
        for (int s = 0; s < 8; s++) {
            float4 pv = p4[s * 96 + kb];
            acc[s] += pv.x * w.x + pv.y * w.y + pv.z * w.z + pv.w * w.w;
        }
    }
#pragma unroll
    for (int s = 0; s < 8; s++) {
        int s_g = sg * 8 + s;
        if (s_g < NSITE)
            pa[((size_t)s_g * 16 + ks) * 96 + co] = acc[s];
    }
}

// ---------------------------------------------------------------------------
// K2b: reduce 16 partials + bias + LN + GELU + kv1 -> k1/v1 [B][3][343][16]
// ---------------------------------------------------------------------------
__global__ __launch_bounds__(96) void k_sr_b(
    const float* __restrict__ pa, const float* __restrict__ sr_b,
    const float* __restrict__ norm_g, const float* __restrict__ norm_b,
    const float* __restrict__ kv1_w, float* __restrict__ k1,
    float* __restrict__ v1)
{
    __shared__ float xs_s[96];
    __shared__ float gx[96];
    const int s_g = blockIdx.x;
    const int b = s_g / NSR, s = s_g % NSR;
    const int co = threadIdx.x;

    const float* pp = pa + (size_t)s_g * 16 * 96 + co;
    float acc = sr_b[co];
#pragma unroll
    for (int ks = 0; ks < 16; ks++) acc += pp[ks * 96];
    xs_s[co] = acc;
    __syncthreads();

    float m = 0.f, m2 = 0.f;
    for (int c = 0; c < 96; c++) { float v = xs_s[c]; m += v; m2 += v * v; }
    m *= (1.f / 96.f);
    float var = m2 * (1.f / 96.f) - m * m;
    float t = (acc - m) * rsqrtf(var + LN_EPS) * norm_g[co] + norm_b[co];
    gx[co] = 0.5f * t * (1.f + erff(t * 0.70710678118654752f));
    __syncthreads();

    const float4* w4 = (const float4*)(kv1_w + co * 96);
    const float4* g4 = (const float4*)gx;
    float a2 = 0.f;
#pragma unroll
    for (int c = 0; c < 24; c++) {
        float4 w = w4[c]; float4 g = g4[c];
        a2 += g.x * w.x + g.y * w.y + g.z * w.z + g.w * w.w;
    }
    int pair = co / 48, h = (co % 48) / 16, e = co % 16;
    float* dst = pair ? v1 : k1;
    dst[(((size_t)b * 3 + h) * NSR + s) * 16 + e] = a2;
}

// ---------------------------------------------------------------------------
// helpers
// ---------------------------------------------------------------------------
__device__ __forceinline__ void ld16_g(const float* p, float* o) {
    const float4* p4 = (const float4*)p;
#pragma unroll
    for (int i = 0; i < 4; i++) {
        float4 v = p4[i];
        o[4 * i] = v.x; o[4 * i + 1] = v.y; o[4 * i + 2] = v.z; o[4 * i + 3] = v.w;
    }
}
__device__ __forceinline__ void st16_g(float* p, const float* o, float scl) {
    float4* p4 = (float4*)p;
#pragma unroll
    for (int i = 0; i < 4; i++)
        p4[i] = make_float4(o[4 * i] * scl, o[4 * i + 1] * scl,
                            o[4 * i + 2] * scl, o[4 * i + 3] * scl);
}
// q -> f16 with SCALE folded in
__device__ __forceinline__ void cvt_qs(const float* qa, h2* qh) {
#pragma unroll
    for (int i = 0; i < 8; i++)
        qh[i] = pk2(qa[2 * i] * SCALE, qa[2 * i + 1] * SCALE);
}
// K row (2 float4 = 8 elems) -> 4 h2 at kl2[4*idx..]
__device__ __forceinline__ void stage_k(h2* kl2, const float4 kv, int idx) {
    kl2[2 * idx]     = pk2(kv.x, kv.y);
    kl2[2 * idx + 1] = pk2(kv.z, kv.w);
}
// pack pair-interleaved V
__device__ __forceinline__ h8 packV(const float4 A, const float4 B) {
    HU u;
    u.p[0] = pk2(A.x, B.x);
    u.p[1] = pk2(A.y, B.y);
    u.p[2] = pk2(A.z, B.z);
    u.p[3] = pk2(A.w, B.w);
    return u.v;
}

// ---------------------------------------------------------------------------
// NQ-query paired attention core. One K/V pair read from LDS (8 x b128) feeds
// NQ queries' QK and PV -> LDS return bytes per query-key cut NQ x vs Q=1.
// NQ=3 balances LDS-BW reduction against per-wave critical path & occupancy.
// ---------------------------------------------------------------------------
template<int NQ>
__device__ __forceinline__ void attn_runpN(
    const h2* kl2, const h2* vp2, int pr0, int pr1,
    const h2 (&qh)[NQ][8], float (&a)[NQ][16], float (&l)[NQ])
{
    const h8* kp = (const h8*)kl2;
    const h8* vp = (const h8*)vp2;
    for (int pr = pr0; pr < pr1; pr++) {
        HU k0, k1, k2, k3, w0, w1, w2, w3;
        k0.v = kp[4 * pr];     k1.v = kp[4 * pr + 1];
        k2.v = kp[4 * pr + 2]; k3.v = kp[4 * pr + 3];
        w0.v = vp[4 * pr];     w1.v = vp[4 * pr + 1];
        w2.v = vp[4 * pr + 2]; w3.v = vp[4 * pr + 3];
#pragma unroll
        for (int j = 0; j < NQ; j++) {
            float sa = 0.f, sb = 0.f, ta = 0.f, tb = 0.f;
#pragma unroll
            for (int i = 0; i < 4; i++) {
                sa = __builtin_amdgcn_fdot2(qh[j][i],     k0.p[i], sa, false);
                sb = __builtin_amdgcn_fdot2(qh[j][4 + i], k1.p[i], sb, false);
                ta = __builtin_amdgcn_fdot2(qh[j][i],     k2.p[i], ta, false);
                tb = __builtin_amdgcn_fdot2(qh[j][4 + i], k3.p[i], tb, false);
            }
            float p0 = __expf(sa + sb), p1 = __expf(ta + tb);
            l[j] += p0 + p1;
            h2 pp = pk2(p0, p1);
#pragma unroll
            for (int i = 0; i < 4; i++) {
                a[j][i]      = __builtin_amdgcn_fdot2(pp, w0.p[i], a[j][i],      false);
                a[j][4 + i]  = __builtin_amdgcn_fdot2(pp, w1.p[i], a[j][4 + i],  false);
                a[j][8 + i]  = __builtin_amdgcn_fdot2(pp, w2.p[i], a[j][8 + i],  false);
                a[j][12 + i] = __builtin_amdgcn_fdot2(pp, w3.p[i], a[j][12 + i], false);
            }
        }
    }
}

// ---------------------------------------------------------------------------
// K3: branch-1 SR attention -> y[:, :, 0:48]
// Block 256 = 2 wave-aligned key-halves x 128 qthreads, Q=3 per thread.
// Grid 6 x 58 = 348 blocks, 1392 waves (5.4/CU): LDS floor < VALU floor.
// pl merge buffer (128 x 51 floats, odd stride -> bank-conflict-free) aliased
// over kl2/vp2 via union; extra sync makes aliasing legal.
// ---------------------------------------------------------------------------
__global__ __launch_bounds__(256) void k_attn1(
    const float* __restrict__ P, const float* __restrict__ k1,
    const float* __restrict__ v1, float* __restrict__ y)
{
    __shared__ union U1 {
        struct { h2 kl2[NSRP * 8]; h2 vp2[NPAIR * 16]; } s;
        float pl[128][51];
    } u;
    const int bh = blockIdx.x;
    const int b = bh / 3, h = bh % 3;
    const float4* ks = (const float4*)(k1 + (size_t)bh * NSR * 16);
    const float4* vs = (const float4*)(v1 + (size_t)bh * NSR * 16);
    const float4 z4 = make_float4(0.f, 0.f, 0.f, 0.f);

    for (int idx = threadIdx.x; idx < NSRP * 4; idx += 256) {
        int m = idx >> 2;
        stage_k(u.s.kl2, (m < NSR) ? ks[idx] : z4, idx);
    }
    for (int idx = threadIdx.x; idx < NPAIR * 2; idx += 256) {
        int pr = idx >> 1, hf = idx & 1;
        int ma = 2 * pr, mb = ma + 1;
        float4 a0 = vs[ma * 4 + hf * 2], a1 = vs[ma * 4 + hf * 2 + 1];
        float4 b0 = z4, b1 = z4;
        if (mb < NSR) { b0 = vs[mb * 4 + hf * 2]; b1 = vs[mb * 4 + hf * 2 + 1]; }
        h8* vph = (h8*)u.s.vp2;
        vph[pr * 4 + hf * 2]     = packV(a0, b0);
        vph[pr * 4 + hf * 2 + 1] = packV(a1, b1);
    }
    __syncthreads();

    const int khalf = threadIdx.x >> 7;         // wave-aligned key split
    const int qloc = threadIdx.x & 127;
    const int qbase = blockIdx.y * 384 + 3 * qloc;

    bool ok[3]; int nq[3];
#pragma unroll
    for (int j = 0; j < 3; j++) {
        int n = qbase + j;
        ok[j] = (n < NTOK);
        nq[j] = ok[j] ? n : 0;
    }

    h2 qh[3][8];
#pragma unroll
    for (int j = 0; j < 3; j++) {
        float qa[16];
        ld16_g(P + ((size_t)b * NTOK + nq[j]) * 288 + 96 + h * 16, qa);
        cvt_qs(qa, qh[j]);
    }

    float a[3][16];
#pragma unroll
    for (int j = 0; j < 3; j++)
#pragma unroll
        for (int e = 0; e < 16; e++) a[j][e] = 0.f;
    float l3[3] = {0.f, 0.f, 0.f};

    attn_runpN<3>(u.s.kl2, u.s.vp2, khalf ? 86 : 0, khalf ? NPAIR : 86, qh, a, l3);
    if (khalf) {
#pragma unroll
        for (int j = 0; j < 3; j++) l3[j] -= 1.f;   // pad key 343
    }

    __syncthreads();        // all kl2/vp2 reads done before pl overwrites them
    if (khalf) {
#pragma unroll
        for (int j = 0; j < 3; j++) {
#pragma unroll
            for (int e = 0; e < 16; e++) u.pl[qloc][j * 17 + e] = a[j][e];
            u.pl[qloc][j * 17 + 16] = l3[j];
        }
    }
    __syncthreads();
    if (!khalf) {
#pragma unroll
        for (int j = 0; j < 3; j++) {
            if (!ok[j]) continue;
            float l = l3[j] + u.pl[qloc][j * 17 + 16];
            float o[16];
#pragma unroll
            for (int e = 0; e < 16; e++) o[e] = a[j][e] + u.pl[qloc][j * 17 + e];
            st16_g(y + ((size_t)b * NTOK + nq[j]) * 96 + h * 16, o, 1.f / l);
        }
    }
}

// ---------------------------------------------------------------------------
// K4: branch-2 windowed attention -> y[:, :, 48:96]
// Block 256 = 2 wave-aligned key-halves x 128 qthreads, Q=3 (q = 3*qloc+j,
// qloc<115 active). Grid 384 blocks, 1536 waves (6/CU).
// ---------------------------------------------------------------------------
__global__ __launch_bounds__(256) void k_attn2(
    const float* __restrict__ P, float* __restrict__ y)
{
    __shared__ union U2 {
        struct { h2 kl2[NSRP * 8]; h2 vp2[NPAIR * 16]; } s;
        float pl[128][51];
    } u;
    const int pb = blockIdx.x;
    const int b = pb / 192;
    const int rem = pb % 192;
    const int h = rem / 64, win = rem % 64;
    const int wh = win >> 4, ww = (win >> 2) & 3, wd = win & 3;
    const int h0 = wh * 7, w0 = ww * 7, d0 = wd * 7;
    const float4 z4 = make_float4(0.f, 0.f, 0.f, 0.f);

    for (int idx = threadIdx.x; idx < NSRP * 4; idx += 256) {
        int m = idx >> 2, e4 = idx & 3;
        float4 kv = z4;
        if (m < NSR) {
            int a = m / 49, bw = (m / 7) % 7, cw = m % 7;
            int n = (h0 + a) * WD + (w0 + bw) * 28 + (d0 + cw);
            kv = *(const float4*)(P + ((size_t)b * NTOK + n) * 288 + 192 + h * 16 + e4 * 4);
        }
        stage_k(u.s.kl2, kv, idx);
    }
    for (int idx = threadIdx.x; idx < NPAIR * 2; idx += 256) {
        int pr = idx >> 1, hf = idx & 1;
        int ma = 2 * pr, mb = ma + 1;
        int aa = ma / 49, ab = (ma / 7) % 7, ac = ma % 7;
        int na = (h0 + aa) * WD + (w0 + ab) * 28 + (d0 + ac);
        const float* sa = P + ((size_t)b * NTOK + na) * 288 + 240 + h * 16 + hf * 8;
        float4 a0 = *(const float4*)sa, a1 = *(const float4*)(sa + 4);
        float4 b0 = z4, b1 = z4;
        if (mb < NSR) {
            int ba = mb / 49, bbw = (mb / 7) % 7, bc = mb % 7;
            int nb = (h0 + ba) * WD + (w0 + bbw) * 28 + (d0 + bc);
            const float* sb = P + ((size_t)b * NTOK + nb) * 288 + 240 + h * 16 + hf * 8;
            b0 = *(const float4*)sb; b1 = *(const float4*)(sb + 4);
        }
        h8* vph = (h8*)u.s.vp2;
        vph[pr * 4 + hf * 2]     = packV(a0, b0);
        vph[pr * 4 + hf * 2 + 1] = packV(a1, b1);
    }
    __syncthreads();

    const int khalf = threadIdx.x >> 7;         // wave-aligned key split
    const int qloc = threadIdx.x & 127;

    bool ok[3]; int n0[3];
#pragma unroll
    for (int j = 0; j < 3; j++) {
        int qq = 3 * qloc + j;
        ok[j] = (qq < NSR);
        int qc = ok[j] ? qq : 0;
        int ai = qc / 49, bi = (qc / 7) % 7, ci = qc % 7;
        n0[j] = (h0 + ai) * WD + (w0 + bi) * 28 + (d0 + ci);
    }

    h2 qh[3][8];
#pragma unroll
    for (int j = 0; j < 3; j++) {
        float qa[16];
        ld16_g(P + ((size_t)b * NTOK + n0[j]) * 288 + 144 + h * 16, qa);
        cvt_qs(qa, qh[j]);
    }

    float a[3][16];
#pragma unroll
    for (int j = 0; j < 3; j++)
#pragma unroll
        for (int e = 0; e < 16; e++) a[j][e] = 0.f;
    float l3[3] = {0.f, 0.f, 0.f};

    attn_runpN<3>(u.s.kl2, u.s.vp2, khalf ? 86 : 0, khalf ? NPAIR : 86, qh, a, l3);
    if (khalf) {
#pragma unroll
        for (int j = 0; j < 3; j++) l3[j] -= 1.f;   // pad key 343
    }

    __syncthreads();        // all kl2/vp2 reads done before pl overwrites them
    if (khalf) {
#pragma unroll
        for (int j = 0; j < 3; j++) {
#pragma unroll
            for (int e = 0; e < 16; e++) u.pl[qloc][j * 17 + e] = a[j][e];
            u.pl[qloc][j * 17 + 16] = l3[j];
        }
    }
    __syncthreads();
    if (!khalf) {
#pragma unroll
        for (int j = 0; j < 3; j++) {
            if (!ok[j]) continue;
            float l = l3[j] + u.pl[qloc][j * 17 + 16];
            float o[16];
#pragma unroll
            for (int e = 0; e < 16; e++) o[e] = a[j][e] + u.pl[qloc][j * 17 + e];
            st16_g(y + ((size_t)b * NTOK + n0[j]) * 96 + 48 + h * 16, o, 1.f / l);
        }
    }
}

// ---------------------------------------------------------------------------
// K5: LePE depthwise 3x3x3 conv over t = P[:,0:96]; y += lepe
// ---------------------------------------------------------------------------
__global__ __launch_bounds__(256) void k_lepe(
    const float* __restrict__ P, const float* __restrict__ cwT,
    const float* __restrict__ cb, float* __restrict__ y)
{
    const int p = blockIdx.x;
    const int l = (p & 7) * 515 + (p >> 3);
    if (l >= LNB) return;
    const int id = l * 256 + threadIdx.x;
    const int g4 = (id % 24) * 4;
    const int nl = id / 24;
    const int n = nl % NTOK;
    const int h = n / WD, w = (n / 28) % 28, d = n % 28;
    const float* Pb = P + (size_t)(nl - n) * 288;

    float4 acc = *(const float4*)(cb + g4);
#pragma unroll
    for (int tap = 0; tap < 27; tap++) {
        const int dh = tap / 9 - 1, dw = (tap / 3) % 3 - 1, dd = tap % 3 - 1;
        const int hh = h + dh, ww = w + dw, d2 = d + dd;
        const bool v = ((unsigned)hh < 28u) & ((unsigned)ww < 28u) & ((unsigned)d2 < 28u);
        const int nn = v ? (hh * WD + ww * 28 + d2) : n;
        const float m = v ? 1.f : 0.f;
        float4 pv = *(const float4*)(Pb + (size_t)nn * 288 + g4);
        float4 wv = *(const float4*)(cwT + tap * 96 + g4);
        acc.x += pv.x * (wv.x * m);
        acc.y += pv.y * (wv.y * m);
        acc.z += pv.z * (wv.z * m);
        acc.w += pv.w * (wv.w * m);
    }
    float4* yp = (float4*)(y + (size_t)nl * 96 + g4);
    float4 cur = *yp;
    cur.x += acc.x; cur.y += acc.y; cur.z += acc.z; cur.w += acc.w;
    *yp = cur;
}

// ---------------------------------------------------------------------------
// K6: out = y @ proj_w^T + proj_b  — packed-f16 fdot2 GEMM, 64 tok x 48 j tile
// ---------------------------------------------------------------------------
__global__ __launch_bounds__(192) void k_out(
    const float* __restrict__ y, const float* __restrict__ proj_w,
    const float* __restrict__ proj_b, float* __restrict__ out)
{
    __shared__ h2 xh[48][68];
    __shared__ h2 wh[48][52];

    const int base = blockIdx.x * 64;
    const int j0 = blockIdx.y * 48;

    for (int it = threadIdx.x; it < 1536; it += 192) {
        int t = it & 63, cq = it >> 6;
        float4 v = *(const float4*)(y + (size_t)(base + t) * 96 + cq * 4);
        xh[cq * 2 + 0][t] = pk2(v.x, v.y);
        xh[cq * 2 + 1][t] = pk2(v.z, v.w);
    }
    for (int it = threadIdx.x; it < 1152; it += 192) {
        int jl = it % 48, cq = it / 48;
        float4 v = *(const float4*)(proj_w + (size_t)(j0 + jl) * 96 + cq * 4);
        wh[cq * 2 + 0][jl] = pk2(v.x, v.y);
        wh[cq * 2 + 1][jl] = pk2(v.z, v.w);
    }
    __syncthreads();

    const int tq = threadIdx.x & 15;
    const int jq = threadIdx.x >> 4;
    float acc[4][4];
#pragma unroll
    for (int i = 0; i < 4; i++)
#pragma unroll
        for (int jj = 0; jj < 4; jj++) acc[i][jj] = 0.f;

    for (int cp = 0; cp < 48; cp++) {
        HU xv, wv;
        xv.v = *(const h8*)(&xh[cp][tq * 4]);
        wv.v = *(const h8*)(&wh[cp][jq * 4]);
#pragma unroll
        for (int i = 0; i < 4; i++)
#pragma unroll
            for (int jj = 0; jj < 4; jj++)
                acc[i][jj] = __builtin_amdgcn_fdot2(xv.p[i], wv.p[jj], acc[i][jj], false);
    }

    float4 bias = *(const float4*)(proj_b + j0 + jq * 4);
#pragma unroll
    for (int i = 0; i < 4; i++) {
        int t = base + tq * 4 + i;
        float4 o = make_float4(acc[i][0] + bias.x, acc[i][1] + bias.y,
                               acc[i][2] + bias.z, acc[i][3] + bias.w);
        *(float4*)(out + (size_t)t * 96 + j0 + jq * 4) = o;
    }
}

extern "C" void kernel_launch(void* const* d_in, const int* in_sizes, int n_in,
                              void* d_out, int out_size, void* d_ws, size_t ws_size,
                              hipStream_t stream) {
    const float* x          = (const float*)d_in[0];
    const float* lepe_lin_w = (const float*)d_in[4];
    const float* lepe_lin_b = (const float*)d_in[5];
    const float* lepe_conv_w= (const float*)d_in[6];
    const float* lepe_conv_b= (const float*)d_in[7];
    const float* sr_w       = (const float*)d_in[8];
    const float* sr_b       = (const float*)d_in[9];
    const float* norm_g     = (const float*)d_in[10];
    const float* norm_b     = (const float*)d_in[11];
    const float* q1_w       = (const float*)d_in[12];
    const float* kv1_w      = (const float*)d_in[13];
    const float* q2_w       = (const float*)d_in[14];
    const float* kv2_w      = (const float*)d_in[15];
    const float* proj_w     = (const float*)d_in[16];
    const float* proj_b     = (const float*)d_in[17];

    float* P   = (float*)d_ws;                        // [B*N][288]
    float* k1  = P + (size_t)BB * NTOK * 288;         // [B][3][343][16]
    float* v1  = k1 + (size_t)BB * 3 * NSR * 16;
    float* y   = v1 + (size_t)BB * 3 * NSR * 16;      // [B*N][96]
    float* pa  = y + (size_t)BB * NTOK * 96;          // [686][16][96]
    float* Wt  = pa + (size_t)NSITE * 16 * 96;        // [1536][96] float4
    float* cwT = Wt + (size_t)1536 * 96 * 4;          // [27][96]

    k_wt<<<587, 256, 0, stream>>>(sr_w, (float4*)Wt, lepe_conv_w, cwT);
    k_proj<<<dim3(686, 6), 192, 0, stream>>>(x, lepe_lin_w, lepe_lin_b, q1_w, q2_w, kv2_w, P);
    k_sr_a<<<dim3(86, 16), 128, 0, stream>>>(x, (const float4*)Wt, pa);
    k_sr_b<<<NSITE, 96, 0, stream>>>(pa, sr_b, norm_g, norm_b, kv1_w, k1, v1);
    k_attn1<<<dim3(6, 58), 256, 0, stream>>>(P, k1, v1, y);
    k_attn2<<<384, 256, 0, stream>>>(P, y);
    k_lepe<<<4120, 256, 0, stream>>>(P, cwT, lepe_conv_b, y);
    k_out<<<dim3(686, 2), 192, 0, stream>>>(y, proj_w, proj_b, (float*)d_out);
}

// Round 5
// 288.443 us; speedup vs baseline: 1.5618x; 1.2922x over previous
//
#include <hip/hip_runtime.h>

#define BB 2
#define NTOK 21952      // 28^3
#define CC 96
#define WD 784          // 28*28
#define NSR 343         // 7^3
#define NKT 22          // key tiles of 16 (352 padded keys)
#define NPADK 9.f       // 352-343 zero-pad keys, each adds exp(0)=1 to lsum
#define NSITE 686       // BB*NSR
#define SCALE 0.25f
#define LN_EPS 1e-5f
#define LNB 4116        // k_lepe logical blocks

typedef _Float16 half_t;
typedef __attribute__((ext_vector_type(2))) _Float16 h2;
typedef __attribute__((ext_vector_type(4))) _Float16 h4;
typedef __attribute__((ext_vector_type(8))) _Float16 h8;
typedef __attribute__((ext_vector_type(4))) float f32x4;
union HU { h8 v; h2 p[4]; };
union H4U { h4 v; h2 p[2]; };

__device__ __forceinline__ h2 pk2(float a, float b) {
    return __builtin_bit_cast(h2, __builtin_amdgcn_cvt_pkrtz(a, b));
}

// ---------------------------------------------------------------------------
// K0: transpose sr_w [96][6144] -> Wt4[1536][96]; also lepe_conv_w -> cwT[27][96]
// ---------------------------------------------------------------------------
__global__ __launch_bounds__(256) void k_wt(
    const float* __restrict__ w, float4* __restrict__ Wt4,
    const float* __restrict__ cw, float* __restrict__ cwT)
{
    const int id = blockIdx.x * 256 + threadIdx.x;
    if (id < 96 * 1536) {
        const int co = id % 96, kbg = id / 96;
        const float4 v = *(const float4*)(w + (size_t)co * 6144 + 4 * kbg);
        Wt4[(size_t)kbg * 96 + co] = v;
    } else if (id < 96 * 1536 + 27 * 96) {
        const int id2 = id - 96 * 1536;
        const int tap = id2 / 96, c = id2 % 96;
        cwT[tap * 96 + c] = cw[c * 27 + tap];
    }
}

// ---------------------------------------------------------------------------
// K1: P[token][288] = x @ [lepe_lin | q1 | q2 | kv2]^T  (+ lepe bias on 0:96)
// ---------------------------------------------------------------------------
__global__ __launch_bounds__(192) void k_proj(
    const float* __restrict__ x, const float* __restrict__ lepe_w,
    const float* __restrict__ lepe_b, const float* __restrict__ q1_w,
    const float* __restrict__ q2_w, const float* __restrict__ kv2_w,
    float* __restrict__ P)
{
    __shared__ h2 xh[48][68];   // [c-pair][token], row 272B (16B aligned)
    __shared__ h2 wh[48][52];   // [c-pair][j],    row 208B (16B aligned)

    const int base = blockIdx.x * 64;
    const int j0 = blockIdx.y * 48;

    for (int it = threadIdx.x; it < 1536; it += 192) {
        int t = it & 63, cq = it >> 6;           // lanes share cq, walk t
        float4 v = *(const float4*)(x + (size_t)(base + t) * 96 + cq * 4);
        xh[cq * 2 + 0][t] = pk2(v.x, v.y);
        xh[cq * 2 + 1][t] = pk2(v.z, v.w);
    }
    for (int it = threadIdx.x; it < 1152; it += 192) {
        int jl = it % 48, cq = it / 48;          // lanes walk jl
        int jg = j0 + jl;
        const float* wrow;
        if (jg < 96)       wrow = lepe_w + jg * 96;
        else if (jg < 144) wrow = q1_w + (jg - 96) * 96;
        else if (jg < 192) wrow = q2_w + (jg - 144) * 96;
        else               wrow = kv2_w + (jg - 192) * 96;
        float4 v = *(const float4*)(wrow + cq * 4);
        wh[cq * 2 + 0][jl] = pk2(v.x, v.y);
        wh[cq * 2 + 1][jl] = pk2(v.z, v.w);
    }
    __syncthreads();

    const int tq = threadIdx.x & 15;
    const int jq = threadIdx.x >> 4;
    float acc[4][4];
#pragma unroll
    for (int i = 0; i < 4; i++)
#pragma unroll
        for (int jj = 0; jj < 4; jj++) acc[i][jj] = 0.f;

    for (int cp = 0; cp < 48; cp++) {
        HU xv, wv;
        xv.v = *(const h8*)(&xh[cp][tq * 4]);
        wv.v = *(const h8*)(&wh[cp][jq * 4]);
#pragma unroll
        for (int i = 0; i < 4; i++)
#pragma unroll
            for (int jj = 0; jj < 4; jj++)
                acc[i][jj] = __builtin_amdgcn_fdot2(xv.p[i], wv.p[jj], acc[i][jj], false);
    }

    float bias[4];
#pragma unroll
    for (int jj = 0; jj < 4; jj++) {
        int jg = j0 + jq * 4 + jj;
        bias[jj] = (jg < 96) ? lepe_b[jg] : 0.f;
    }
#pragma unroll
    for (int i = 0; i < 4; i++) {
        int t = base + tq * 4 + i;
        float4 o = make_float4(acc[i][0] + bias[0], acc[i][1] + bias[1],
                               acc[i][2] + bias[2], acc[i][3] + bias[3]);
        *(float4*)(P + (size_t)t * 288 + j0 + jq * 4) = o;
    }
}

// ---------------------------------------------------------------------------
// K2a: SR conv split-K GEMM. grid (86 site-groups x 16 k-splits), block 128.
// ---------------------------------------------------------------------------
__global__ __launch_bounds__(128) void k_sr_a(
    const float* __restrict__ x, const float4* __restrict__ Wt4,
    float* __restrict__ pa)
{
    __shared__ float patch[8 * 384];
    const int sg = blockIdx.x, ks = blockIdx.y;
    const int ci0 = ks * 6;

    for (int pr = threadIdx.x; pr < 512; pr += 128) {
        int s = pr >> 6, p = pr & 63;
        int s_g = sg * 8 + s; if (s_g > NSITE - 1) s_g = NSITE - 1;
        int b = s_g / NSR, sloc = s_g % NSR;
        int si = sloc / 49, sj = (sloc / 7) % 7, sk = sloc % 7;
        int a = p >> 4, q = (p >> 2) & 3, r = p & 3;
        int n = (4 * si + a) * WD + (4 * sj + q) * 28 + (4 * sk + r);
        const float2* xp = (const float2*)(x + ((size_t)b * NTOK + n) * 96 + ci0);
        float2 v0 = xp[0], v1 = xp[1], v2 = xp[2];
        int base = s * 384 + p;
        patch[base +   0] = v0.x; patch[base +  64] = v0.y;
        patch[base + 128] = v1.x; patch[base + 192] = v1.y;
        patch[base + 256] = v2.x; patch[base + 320] = v2.y;
    }
    __syncthreads();

    const int co = threadIdx.x;
    if (co >= 96) return;
    float acc[8];
#pragma unroll
    for (int s = 0; s < 8; s++) acc[s] = 0.f;
    const float4* p4 = (const float4*)patch;
    const float4* wb = Wt4 + (size_t)ks * 96 * 96 + co;
    for (int kb = 0; kb < 96; kb++) {
        float4 w = wb[(size_t)kb * 96];
#pragma unroll
        for (int s = 0; s < 8; s++) {
            float4 pv = p4[s * 96 + kb];
            acc[s] += pv.x * w.x + pv.y * w.y + pv.z * w.z + pv.w * w.w;
        }
    }
#pragma unroll
    for (int s = 0; s < 8; s++) {
        int s_g = sg * 8 + s;
        if (s_g < NSITE)
            pa[((size_t)s_g * 16 + ks) * 96 + co] = acc[s];
    }
}

// ---------------------------------------------------------------------------
// K2b: reduce 16 partials + bias + LN + GELU + kv1 -> k1/v1 [B][3][343][16]
// ---------------------------------------------------------------------------
__global__ __launch_bounds__(96) void k_sr_b(
    const float* __restrict__ pa, const float* __restrict__ sr_b,
    const float* __restrict__ norm_g, const float* __restrict__ norm_b,
    const float* __restrict__ kv1_w, float* __restrict__ k1,
    float* __restrict__ v1)
{
    __shared__ float xs_s[96];
    __shared__ float gx[96];
    const int s_g = blockIdx.x;
    const int b = s_g / NSR, s = s_g % NSR;
    const int co = threadIdx.x;

    const float* pp = pa + (size_t)s_g * 16 * 96 + co;
    float acc = sr_b[co];
#pragma unroll
    for (int ks = 0; ks < 16; ks++) acc += pp[ks * 96];
    xs_s[co] = acc;
    __syncthreads();

    float m = 0.f, m2 = 0.f;
    for (int c = 0; c < 96; c++) { float v = xs_s[c]; m += v; m2 += v * v; }
    m *= (1.f / 96.f);
    float var = m2 * (1.f / 96.f) - m * m;
    float t = (acc - m) * rsqrtf(var + LN_EPS) * norm_g[co] + norm_b[co];
    gx[co] = 0.5f * t * (1.f + erff(t * 0.70710678118654752f));
    __syncthreads();

    const float4* w4 = (const float4*)(kv1_w + co * 96);
    const float4* g4 = (const float4*)gx;
    float a2 = 0.f;
#pragma unroll
    for (int c = 0; c < 24; c++) {
        float4 w = w4[c]; float4 g = g4[c];
        a2 += g.x * w.x + g.y * w.y + g.z * w.z + g.w * w.w;
    }
    int pair = co / 48, h = (co % 48) / 16, e = co % 16;
    float* dst = pair ? v1 : k1;
    dst[(((size_t)b * 3 + h) * NSR + s) * 16 + e] = a2;
}

// ---------------------------------------------------------------------------
// MFMA attention core (v_mfma_f32_16x16x16_f16, swapped operands).
//   S^T tile = mfma(A=K_tile, B=Q_tile):  A: lane={key=l&15, k=4*(l>>4)+i}
//                                         B: lane={q =l&15, k=4*(l>>4)+i}
//                                         D: lane={q =l&15, key=4*(l>>4)+r}
//   exp in-lane; P^T already sits in B-operand layout for
//   O^T += mfma(A=V^T_tile, B=P^T):       A: lane={d =l&15, key=4*(l>>4)+i}
//                                         D: lane={q =l&15, d =4*(l>>4)+r}
// KA/VA are pre-packed per-lane 8B slots -> conflict-free ds_read_b64.
// ---------------------------------------------------------------------------
__device__ __forceinline__ void attn_mfma_core(
    const h4* __restrict__ KA, const h4* __restrict__ VA, int lane,
    h4 qb, f32x4& o, float& lsum)
{
    o = (f32x4){0.f, 0.f, 0.f, 0.f};
    lsum = 0.f;
    for (int t = 0; t < NKT; t++) {
        h4 ka = KA[t * 64 + lane];
        f32x4 s = __builtin_amdgcn_mfma_f32_16x16x16f16(
            ka, qb, (f32x4){0.f, 0.f, 0.f, 0.f}, 0, 0, 0);
        float p0 = __expf(s[0]), p1 = __expf(s[1]);
        float p2 = __expf(s[2]), p3 = __expf(s[3]);
        lsum += (p0 + p1) + (p2 + p3);
        H4U pb;
        pb.p[0] = pk2(p0, p1);
        pb.p[1] = pk2(p2, p3);
        h4 va = VA[t * 64 + lane];
        o = __builtin_amdgcn_mfma_f32_16x16x16f16(va, pb.v, o, 0, 0, 0);
    }
}

// ---------------------------------------------------------------------------
// K3: branch-1 SR attention -> y[:, :, 0:48]   (MFMA)
// grid (6 bh, 86 q-groups), 512 thr = 8 waves; each wave 2 q-tiles of 16.
// K/V from k1/v1 [bh][343][16] f32, staged once into A-operand layout.
// ---------------------------------------------------------------------------
__global__ __launch_bounds__(512) void k_attn1(
    const float* __restrict__ P, const float* __restrict__ k1,
    const float* __restrict__ v1, float* __restrict__ y)
{
    __shared__ h4 KA[NKT * 64];
    __shared__ h4 VA[NKT * 64];
    const int bh = blockIdx.x;
    const int b = bh / 3, h = bh % 3;
    const float* ksrc = k1 + (size_t)bh * NSR * 16;
    const float* vsrc = v1 + (size_t)bh * NSR * 16;

    // stage K: slot lane l of tile t holds K[16t+(l&15)][4*(l>>4)..+3]
    for (int s = threadIdx.x; s < NKT * 64; s += 512) {
        int t = s >> 6, l = s & 63;
        int key = t * 16 + (l & 15);
        int dg = (l >> 4) * 4;
        H4U tmp; tmp.p[0] = pk2(0.f, 0.f); tmp.p[1] = pk2(0.f, 0.f);
        if (key < NSR) {
            float4 v = *(const float4*)(ksrc + (size_t)key * 16 + dg);
            tmp.p[0] = pk2(v.x, v.y); tmp.p[1] = pk2(v.z, v.w);
        }
        KA[s] = tmp.v;
    }
    // stage V^T: slot lane l of tile t holds V[16t+4*(l>>4)+i][l&15], i=0..3
    for (int s = threadIdx.x; s < NKT * 64; s += 512) {
        int t = s >> 6, l = s & 63;
        int dim = l & 15;
        int k0 = t * 16 + (l >> 4) * 4;
        float f[4];
#pragma unroll
        for (int i = 0; i < 4; i++) {
            int key = k0 + i;
            f[i] = (key < NSR) ? vsrc[(size_t)key * 16 + dim] : 0.f;
        }
        H4U tmp; tmp.p[0] = pk2(f[0], f[1]); tmp.p[1] = pk2(f[2], f[3]);
        VA[s] = tmp.v;
    }
    __syncthreads();

    const int lane = threadIdx.x & 63;
    const int wid = threadIdx.x >> 6;

    for (int qi = wid; qi < 16; qi += 8) {
        int qt = blockIdx.y * 16 + qi;
        if (qt >= 1372) break;                      // wave-uniform
        int tok = qt * 16 + (lane & 15);
        float4 qv = *(const float4*)(P + ((size_t)b * NTOK + tok) * 288
                                     + 96 + h * 16 + (lane >> 4) * 4);
        H4U qb;
        qb.p[0] = pk2(qv.x * SCALE, qv.y * SCALE);
        qb.p[1] = pk2(qv.z * SCALE, qv.w * SCALE);

        f32x4 o; float lsum;
        attn_mfma_core(KA, VA, lane, qb.v, o, lsum);
        lsum += __shfl_xor(lsum, 16);
        lsum += __shfl_xor(lsum, 32);
        float inv = 1.f / (lsum - NPADK);
        float4 out = make_float4(o[0] * inv, o[1] * inv, o[2] * inv, o[3] * inv);
        *(float4*)(y + ((size_t)b * NTOK + tok) * 96 + h * 16 + (lane >> 4) * 4) = out;
    }
}

// ---------------------------------------------------------------------------
// K4: branch-2 windowed attention -> y[:, :, 48:96]   (MFMA)
// 384 blocks (b,h,win), 512 thr = 8 waves; 22 q-tiles looped over waves.
// K/V gathered from P (kv2 slice), staged once into A-operand layout.
// ---------------------------------------------------------------------------
__global__ __launch_bounds__(512) void k_attn2(
    const float* __restrict__ P, float* __restrict__ y)
{
    __shared__ h4 KA[NKT * 64];
    __shared__ h4 VA[NKT * 64];
    const int pb = blockIdx.x;
    const int b = pb / 192;
    const int rem = pb % 192;
    const int h = rem / 64, win = rem % 64;
    const int wh = win >> 4, ww = (win >> 2) & 3, wd = win & 3;
    const int h0 = wh * 7, w0 = ww * 7, d0 = wd * 7;
    const size_t bOff = (size_t)b * NTOK;

    for (int s = threadIdx.x; s < NKT * 64; s += 512) {
        int t = s >> 6, l = s & 63;
        int key = t * 16 + (l & 15);
        int dg = (l >> 4) * 4;
        H4U tmp; tmp.p[0] = pk2(0.f, 0.f); tmp.p[1] = pk2(0.f, 0.f);
        if (key < NSR) {
            int a = key / 49, bw = (key / 7) % 7, cw = key % 7;
            int n = (h0 + a) * WD + (w0 + bw) * 28 + (d0 + cw);
            float4 v = *(const float4*)(P + (bOff + n) * 288 + 192 + h * 16 + dg);
            tmp.p[0] = pk2(v.x, v.y); tmp.p[1] = pk2(v.z, v.w);
        }
        KA[s] = tmp.v;
    }
    for (int s = threadIdx.x; s < NKT * 64; s += 512) {
        int t = s >> 6, l = s & 63;
        int dim = l & 15;
        int k0 = t * 16 + (l >> 4) * 4;
        float f[4];
#pragma unroll
        for (int i = 0; i < 4; i++) {
            int key = k0 + i;
            float val = 0.f;
            if (key < NSR) {
                int a = key / 49, bw = (key / 7) % 7, cw = key % 7;
                int n = (h0 + a) * WD + (w0 + bw) * 28 + (d0 + cw);
                val = P[(bOff + n) * 288 + 240 + h * 16 + dim];
            }
            f[i] = val;
        }
        H4U tmp; tmp.p[0] = pk2(f[0], f[1]); tmp.p[1] = pk2(f[2], f[3]);
        VA[s] = tmp.v;
    }
    __syncthreads();

    const int lane = threadIdx.x & 63;
    const int wid = threadIdx.x >> 6;

    for (int qt = wid; qt < NKT; qt += 8) {
        int q = qt * 16 + (lane & 15);
        int qc = (q < NSR) ? q : (NSR - 1);
        int ai = qc / 49, bi = (qc / 7) % 7, ci = qc % 7;
        int tok = (h0 + ai) * WD + (w0 + bi) * 28 + (d0 + ci);
        float4 qv = *(const float4*)(P + (bOff + tok) * 288
                                     + 144 + h * 16 + (lane >> 4) * 4);
        H4U qb;
        qb.p[0] = pk2(qv.x * SCALE, qv.y * SCALE);
        qb.p[1] = pk2(qv.z * SCALE, qv.w * SCALE);

        f32x4 o; float lsum;
        attn_mfma_core(KA, VA, lane, qb.v, o, lsum);
        lsum += __shfl_xor(lsum, 16);
        lsum += __shfl_xor(lsum, 32);
        float inv = 1.f / (lsum - NPADK);
        if (q < NSR) {
            float4 out = make_float4(o[0] * inv, o[1] * inv, o[2] * inv, o[3] * inv);
            *(float4*)(y + (bOff + tok) * 96 + 48 + h * 16 + (lane >> 4) * 4) = out;
        }
    }
}

// ---------------------------------------------------------------------------
// K5: LePE depthwise 3x3x3 conv over t = P[:,0:96]; y += lepe
// ---------------------------------------------------------------------------
__global__ __launch_bounds__(256) void k_lepe(
    const float* __restrict__ P, const float* __restrict__ cwT,
    const float* __restrict__ cb, float* __restrict__ y)
{
    const int p = blockIdx.x;
    const int l = (p & 7) * 515 + (p >> 3);
    if (l >= LNB) return;
    const int id = l * 256 + threadIdx.x;
    const int g4 = (id % 24) * 4;
    const int nl = id / 24;
    const int n = nl % NTOK;
    const int h = n / WD, w = (n / 28) % 28, d = n % 28;
    const float* Pb = P + (size_t)(nl - n) * 288;

    float4 acc = *(const float4*)(cb + g4);
#pragma unroll
    for (int tap = 0; tap < 27; tap++) {
        const int dh = tap / 9 - 1, dw = (tap / 3) % 3 - 1, dd = tap % 3 - 1;
        const int hh = h + dh, ww = w + dw, d2 = d + dd;
        const bool v = ((unsigned)hh < 28u) & ((unsigned)ww < 28u) & ((unsigned)d2 < 28u);
        const int nn = v ? (hh * WD + ww * 28 + d2) : n;
        const float m = v ? 1.f : 0.f;
        float4 pv = *(const float4*)(Pb + (size_t)nn * 288 + g4);
        float4 wv = *(const float4*)(cwT + tap * 96 + g4);
        acc.x += pv.x * (wv.x * m);
        acc.y += pv.y * (wv.y * m);
        acc.z += pv.z * (wv.z * m);
        acc.w += pv.w * (wv.w * m);
    }
    float4* yp = (float4*)(y + (size_t)nl * 96 + g4);
    float4 cur = *yp;
    cur.x += acc.x; cur.y += acc.y; cur.z += acc.z; cur.w += acc.w;
    *yp = cur;
}

// ---------------------------------------------------------------------------
// K6: out = y @ proj_w^T + proj_b  — packed-f16 fdot2 GEMM, 64 tok x 48 j tile
// ---------------------------------------------------------------------------
__global__ __launch_bounds__(192) void k_out(
    const float* __restrict__ y, const float* __restrict__ proj_w,
    const float* __restrict__ proj_b, float* __restrict__ out)
{
    __shared__ h2 xh[48][68];
    __shared__ h2 wh[48][52];

    const int base = blockIdx.x * 64;
    const int j0 = blockIdx.y * 48;

    for (int it = threadIdx.x; it < 1536; it += 192) {
        int t = it & 63, cq = it >> 6;
        float4 v = *(const float4*)(y + (size_t)(base + t) * 96 + cq * 4);
        xh[cq * 2 + 0][t] = pk2(v.x, v.y);
        xh[cq * 2 + 1][t] = pk2(v.z, v.w);
    }
    for (int it = threadIdx.x; it < 1152; it += 192) {
        int jl = it % 48, cq = it / 48;
        float4 v = *(const float4*)(proj_w + (size_t)(j0 + jl) * 96 + cq * 4);
        wh[cq * 2 + 0][jl] = pk2(v.x, v.y);
        wh[cq * 2 + 1][jl] = pk2(v.z, v.w);
    }
    __syncthreads();

    const int tq = threadIdx.x & 15;
    const int jq = threadIdx.x >> 4;
    float acc[4][4];
#pragma unroll
    for (int i = 0; i < 4; i++)
#pragma unroll
        for (int jj = 0; jj < 4; jj++) acc[i][jj] = 0.f;

    for (int cp = 0; cp < 48; cp++) {
        HU xv, wv;
        xv.v = *(const h8*)(&xh[cp][tq * 4]);
        wv.v = *(const h8*)(&wh[cp][jq * 4]);
#pragma unroll
        for (int i = 0; i < 4; i++)
#pragma unroll
            for (int jj = 0; jj < 4; jj++)
                acc[i][jj] = __builtin_amdgcn_fdot2(xv.p[i], wv.p[jj], acc[i][jj], false);
    }

    float4 bias = *(const float4*)(proj_b + j0 + jq * 4);
#pragma unroll
    for (int i = 0; i < 4; i++) {
        int t = base + tq * 4 + i;
        float4 o = make_float4(acc[i][0] + bias.x, acc[i][1] + bias.y,
                               acc[i][2] + bias.z, acc[i][3] + bias.w);
        *(float4*)(out + (size_t)t * 96 + j0 + jq * 4) = o;
    }
}

extern "C" void kernel_launch(void* const* d_in, const int* in_sizes, int n_in,
                              void* d_out, int out_size, void* d_ws, size_t ws_size,
                              hipStream_t stream) {
    const float* x          = (const float*)d_in[0];
    const float* lepe_lin_w = (const float*)d_in[4];
    const float* lepe_lin_b = (const float*)d_in[5];
    const float* lepe_conv_w= (const float*)d_in[6];
    const float* lepe_conv_b= (const float*)d_in[7];
    const float* sr_w       = (const float*)d_in[8];
    const float* sr_b       = (const float*)d_in[9];
    const float* norm_g     = (const float*)d_in[10];
    const float* norm_b     = (const float*)d_in[11];
    const float* q1_w       = (const float*)d_in[12];
    const float* kv1_w      = (const float*)d_in[13];
    const float* q2_w       = (const float*)d_in[14];
    const float* kv2_w      = (const float*)d_in[15];
    const float* proj_w     = (const float*)d_in[16];
    const float* proj_b     = (const float*)d_in[17];

    float* P   = (float*)d_ws;                        // [B*N][288]
    float* k1  = P + (size_t)BB * NTOK * 288;         // [B][3][343][16]
    float* v1  = k1 + (size_t)BB * 3 * NSR * 16;
    float* y   = v1 + (size_t)BB * 3 * NSR * 16;      // [B*N][96]
    float* pa  = y + (size_t)BB * NTOK * 96;          // [686][16][96]
    float* Wt  = pa + (size_t)NSITE * 16 * 96;        // [1536][96] float4
    float* cwT = Wt + (size_t)1536 * 96 * 4;          // [27][96]

    k_wt<<<587, 256, 0, stream>>>(sr_w, (float4*)Wt, lepe_conv_w, cwT);
    k_proj<<<dim3(686, 6), 192, 0, stream>>>(x, lepe_lin_w, lepe_lin_b, q1_w, q2_w, kv2_w, P);
    k_sr_a<<<dim3(86, 16), 128, 0, stream>>>(x, (const float4*)Wt, pa);
    k_sr_b<<<NSITE, 96, 0, stream>>>(pa, sr_b, norm_g, norm_b, kv1_w, k1, v1);
    k_attn1<<<dim3(6, 86), 512, 0, stream>>>(P, k1, v1, y);
    k_attn2<<<384, 512, 0, stream>>>(P, y);
    k_lepe<<<4120, 256, 0, stream>>>(P, cwT, lepe_conv_b, y);
    k_out<<<dim3(686, 2), 192, 0, stream>>>(y, proj_w, proj_b, (float*)d_out);
}

// Round 7
// 258.217 us; speedup vs baseline: 1.7446x; 1.1171x over previous
//
#include <hip/hip_runtime.h>

#define BB 2
#define NTOK 21952      // 28^3
#define CC 96
#define WD 784          // 28*28
#define NSR 343         // 7^3
#define NKT 22          // key tiles of 16 (352 padded keys)
#define NPADK 9.f       // 352-343 zero-pad keys, each adds exp(0)=1 to lsum
#define NSITE 686       // BB*NSR
#define SCALE 0.25f
#define LN_EPS 1e-5f
#define LNB 4116        // k_lepe logical blocks
#define WSA_N (6*16*24*64)   // 147456 h4 slots: [ct][ks][kt][lane]
#define WPA_N (18*6*64)      // 6912  h4 slots: [ct][kt][lane]

typedef _Float16 half_t;
typedef __attribute__((ext_vector_type(2))) _Float16 h2;
typedef __attribute__((ext_vector_type(4))) _Float16 h4;
typedef __attribute__((ext_vector_type(8))) _Float16 h8;
typedef __attribute__((ext_vector_type(4))) float f32x4;
union HU { h8 v; h2 p[4]; };
union H4U { h4 v; h2 p[2]; };

__device__ __forceinline__ h2 pk2(float a, float b) {
    return __builtin_bit_cast(h2, __builtin_amdgcn_cvt_pkrtz(a, b));
}

// ---------------------------------------------------------------------------
// K0: pack weights into MFMA A-frag layouts.
//   WSA: SR conv weights [co][ci*64+p] -> [ct 6][ks 16][kt 24][lane 64] h4,
//        K ordering k = p*96 + c  (position-major, matches k_sr_a staging).
//   WPA: [lepe|q1|q2|kv2] rows  -> [ct 18][kt 6][lane 64] h4, k = channel.
//   cwT: lepe conv taps transposed [27][96].
// A-frag: lane l = { row co = l&15, k = 4*(l>>4)+i }.
// ---------------------------------------------------------------------------
__global__ __launch_bounds__(256) void k_wt(
    const float* __restrict__ w, h4* __restrict__ WSA, h4* __restrict__ WPA,
    const float* __restrict__ lepe_w, const float* __restrict__ q1_w,
    const float* __restrict__ q2_w, const float* __restrict__ kv2_w,
    const float* __restrict__ cw, float* __restrict__ cwT)
{
    const int id = blockIdx.x * 256 + threadIdx.x;
    if (id < WSA_N) {
        const int lane = id & 63;
        const int kt = (id >> 6) % 24;
        const int ks = ((id >> 6) / 24) % 16;
        const int ct = (id >> 6) / 384;
        const int co = ct * 16 + (lane & 15);
        const int kb = ks * 384 + kt * 16 + 4 * (lane >> 4);
        const int p = kb / 96, c = kb % 96;
        float f[4];
#pragma unroll
        for (int i = 0; i < 4; i++)
            f[i] = w[(size_t)co * 6144 + (c + i) * 64 + p];
        H4U t; t.p[0] = pk2(f[0], f[1]); t.p[1] = pk2(f[2], f[3]);
        WSA[id] = t.v;
    } else if (id < WSA_N + WPA_N) {
        const int id2 = id - WSA_N;
        const int lane = id2 & 63;
        const int kt = (id2 >> 6) % 6;
        const int ct = (id2 >> 6) / 6;
        const int co = ct * 16 + (lane & 15);
        const int k = kt * 16 + 4 * (lane >> 4);
        const float* wrow;
        if (co < 96)       wrow = lepe_w + co * 96;
        else if (co < 144) wrow = q1_w + (co - 96) * 96;
        else if (co < 192) wrow = q2_w + (co - 144) * 96;
        else               wrow = kv2_w + (co - 192) * 96;
        float4 v = *(const float4*)(wrow + k);
        H4U t; t.p[0] = pk2(v.x, v.y); t.p[1] = pk2(v.z, v.w);
        WPA[id2] = t.v;
    } else if (id < WSA_N + WPA_N + 27 * 96) {
        const int id3 = id - WSA_N - WPA_N;
        const int tap = id3 / 96, c = id3 % 96;
        cwT[tap * 96 + c] = cw[c * 27 + tap];
    }
}

// ---------------------------------------------------------------------------
// K1: P[token][288] = x @ [lepe_lin | q1 | q2 | kv2]^T (+ lepe bias on 0:96)
// MFMA: block = 64 tokens, ALL 288 outputs (x fetched exactly once).
// 4 waves; wave w handles co-tiles ct = w, w+4, ... B-frags (x) staged in LDS
// once, shared by all waves. A-frags (weights) streamed from WPA (L2-hot).
// D lane = { tok = l&15, co = 4*(l>>4)+r } -> float4 store.
// ---------------------------------------------------------------------------
__global__ __launch_bounds__(256) void k_proj(
    const float* __restrict__ x, const h4* __restrict__ WPA,
    const float* __restrict__ lepe_b, float* __restrict__ P)
{
    __shared__ h4 BX[4 * 6 * 64];    // [tt][kt][lane]
    const int blk = blockIdx.x;
    const int tid = threadIdx.x;

    for (int s = tid; s < 1536; s += 256) {
        int lane = s & 63;
        int kt = (s >> 6) % 6;
        int tt = (s >> 6) / 6;
        int tok = blk * 64 + tt * 16 + (lane & 15);
        int k0 = kt * 16 + 4 * (lane >> 4);
        float4 v = *(const float4*)(x + (size_t)tok * 96 + k0);
        H4U t; t.p[0] = pk2(v.x, v.y); t.p[1] = pk2(v.z, v.w);
        BX[s] = t.v;
    }
    __syncthreads();

    const int lane = tid & 63;
    const int wid = tid >> 6;

    h4 bx[24];
#pragma unroll
    for (int q = 0; q < 24; q++) bx[q] = BX[q * 64 + lane];

    for (int ct = wid; ct < 18; ct += 4) {
        f32x4 acc[4];
#pragma unroll
        for (int tt = 0; tt < 4; tt++) acc[tt] = (f32x4){0.f, 0.f, 0.f, 0.f};
#pragma unroll
        for (int kt = 0; kt < 6; kt++) {
            h4 wa = WPA[(ct * 6 + kt) * 64 + lane];
#pragma unroll
            for (int tt = 0; tt < 4; tt++)
                acc[tt] = __builtin_amdgcn_mfma_f32_16x16x16f16(
                    wa, bx[tt * 6 + kt], acc[tt], 0, 0, 0);
        }
        float4 b4 = make_float4(0.f, 0.f, 0.f, 0.f);
        if (ct < 6) b4 = *(const float4*)(lepe_b + ct * 16 + 4 * (lane >> 4));
#pragma unroll
        for (int tt = 0; tt < 4; tt++) {
            int tok = blk * 64 + tt * 16 + (lane & 15);
            float4 o = make_float4(acc[tt][0] + b4.x, acc[tt][1] + b4.y,
                                   acc[tt][2] + b4.z, acc[tt][3] + b4.w);
            *(float4*)(P + (size_t)tok * 288 + ct * 16 + 4 * (lane >> 4)) = o;
        }
    }
}

// ---------------------------------------------------------------------------
// K2a: SR conv as MFMA GEMM. grid (43 site-tiles x 16 K-splits), 1 wave.
// K ordering k = p*96 + c: each (site, position) row of x (384 B) is read in
// full by exactly one block -> zero over-fetch. B-frags (patch) live directly
// in registers (lane mapping == staging mapping; no LDS, no sync).
// D lane = { site = l&15, co = 4*(l>>4)+r } -> float4 to pa[site][ks][co].
// ---------------------------------------------------------------------------
__global__ __launch_bounds__(64) void k_sr_a(
    const float* __restrict__ x, const h4* __restrict__ WSA,
    float* __restrict__ pa)
{
    const int mb = blockIdx.x;       // 0..42
    const int ks = blockIdx.y;       // 0..15
    const int lane = threadIdx.x;

    int site = mb * 16 + (lane & 15);
    const int site_g = site;
    if (site > NSITE - 1) site = NSITE - 1;
    const int b = site / NSR, sloc = site % NSR;
    const int si = sloc / 49, sj = (sloc / 7) % 7, sk = sloc % 7;

    h4 bx[24];
#pragma unroll
    for (int kt = 0; kt < 24; kt++) {
        int kg = ks * 384 + kt * 16 + 4 * (lane >> 4);
        int p = kg / 96, c = kg % 96;
        int a = p >> 4, q = (p >> 2) & 3, r = p & 3;
        int n = (4 * si + a) * WD + (4 * sj + q) * 28 + (4 * sk + r);
        float4 v = *(const float4*)(x + ((size_t)b * NTOK + n) * 96 + c);
        H4U t; t.p[0] = pk2(v.x, v.y); t.p[1] = pk2(v.z, v.w);
        bx[kt] = t.v;
    }

    for (int ct = 0; ct < 6; ct++) {
        f32x4 acc = (f32x4){0.f, 0.f, 0.f, 0.f};
#pragma unroll
        for (int kt = 0; kt < 24; kt++) {
            h4 wa = WSA[(size_t)(((ct * 16 + ks) * 24) + kt) * 64 + lane];
            acc = __builtin_amdgcn_mfma_f32_16x16x16f16(wa, bx[kt], acc, 0, 0, 0);
        }
        if (site_g < NSITE) {
            *(float4*)(pa + ((size_t)site_g * 16 + ks) * 96 + ct * 16
                       + 4 * (lane >> 4)) =
                make_float4(acc[0], acc[1], acc[2], acc[3]);
        }
    }
}

// ---------------------------------------------------------------------------
// K2b: reduce 16 partials + bias + LN + GELU + kv1 -> k1/v1 [B][3][343][16]
// ---------------------------------------------------------------------------
__global__ __launch_bounds__(96) void k_sr_b(
    const float* __restrict__ pa, const float* __restrict__ sr_b,
    const float* __restrict__ norm_g, const float* __restrict__ norm_b,
    const float* __restrict__ kv1_w, float* __restrict__ k1,
    float* __restrict__ v1)
{
    __shared__ float xs_s[96];
    __shared__ float gx[96];
    const int s_g = blockIdx.x;
    const int b = s_g / NSR, s = s_g % NSR;
    const int co = threadIdx.x;

    const float* pp = pa + (size_t)s_g * 16 * 96 + co;
    float acc = sr_b[co];
#pragma unroll
    for (int ks = 0; ks < 16; ks++) acc += pp[ks * 96];
    xs_s[co] = acc;
    __syncthreads();

    float m = 0.f, m2 = 0.f;
    for (int c = 0; c < 96; c++) { float v = xs_s[c]; m += v; m2 += v * v; }
    m *= (1.f / 96.f);
    float var = m2 * (1.f / 96.f) - m * m;
    float t = (acc - m) * rsqrtf(var + LN_EPS) * norm_g[co] + norm_b[co];
    gx[co] = 0.5f * t * (1.f + erff(t * 0.70710678118654752f));
    __syncthreads();

    const float4* w4 = (const float4*)(kv1_w + co * 96);
    const float4* g4 = (const float4*)gx;
    float a2 = 0.f;
#pragma unroll
    for (int c = 0; c < 24; c++) {
        float4 w = w4[c]; float4 g = g4[c];
        a2 += g.x * w.x + g.y * w.y + g.z * w.z + g.w * w.w;
    }
    int pair = co / 48, h = (co % 48) / 16, e = co % 16;
    float* dst = pair ? v1 : k1;
    dst[(((size_t)b * 3 + h) * NSR + s) * 16 + e] = a2;
}

// ---------------------------------------------------------------------------
// MFMA attention core (v_mfma_f32_16x16x16_f16, swapped operands).
// ---------------------------------------------------------------------------
__device__ __forceinline__ void attn_mfma_core(
    const h4* __restrict__ KA, const h4* __restrict__ VA, int lane,
    h4 qb, f32x4& o, float& lsum)
{
    o = (f32x4){0.f, 0.f, 0.f, 0.f};
    lsum = 0.f;
    for (int t = 0; t < NKT; t++) {
        h4 ka = KA[t * 64 + lane];
        f32x4 s = __builtin_amdgcn_mfma_f32_16x16x16f16(
            ka, qb, (f32x4){0.f, 0.f, 0.f, 0.f}, 0, 0, 0);
        float p0 = __expf(s[0]), p1 = __expf(s[1]);
        float p2 = __expf(s[2]), p3 = __expf(s[3]);
        lsum += (p0 + p1) + (p2 + p3);
        H4U pb;
        pb.p[0] = pk2(p0, p1);
        pb.p[1] = pk2(p2, p3);
        h4 va = VA[t * 64 + lane];
        o = __builtin_amdgcn_mfma_f32_16x16x16f16(va, pb.v, o, 0, 0, 0);
    }
}

// ---------------------------------------------------------------------------
// K3: branch-1 SR attention -> y[:, :, 0:48]   (MFMA)
// ---------------------------------------------------------------------------
__global__ __launch_bounds__(512) void k_attn1(
    const float* __restrict__ P, const float* __restrict__ k1,
    const float* __restrict__ v1, float* __restrict__ y)
{
    __shared__ h4 KA[NKT * 64];
    __shared__ h4 VA[NKT * 64];
    const int bh = blockIdx.x;
    const int b = bh / 3, h = bh % 3;
    const float* ksrc = k1 + (size_t)bh * NSR * 16;
    const float* vsrc = v1 + (size_t)bh * NSR * 16;

    for (int s = threadIdx.x; s < NKT * 64; s += 512) {
        int t = s >> 6, l = s & 63;
        int key = t * 16 + (l & 15);
        int dg = (l >> 4) * 4;
        H4U tmp; tmp.p[0] = pk2(0.f, 0.f); tmp.p[1] = pk2(0.f, 0.f);
        if (key < NSR) {
            float4 v = *(const float4*)(ksrc + (size_t)key * 16 + dg);
            tmp.p[0] = pk2(v.x, v.y); tmp.p[1] = pk2(v.z, v.w);
        }
        KA[s] = tmp.v;
    }
    for (int s = threadIdx.x; s < NKT * 64; s += 512) {
        int t = s >> 6, l = s & 63;
        int dim = l & 15;
        int k0 = t * 16 + (l >> 4) * 4;
        float f[4];
#pragma unroll
        for (int i = 0; i < 4; i++) {
            int key = k0 + i;
            f[i] = (key < NSR) ? vsrc[(size_t)key * 16 + dim] : 0.f;
        }
        H4U tmp; tmp.p[0] = pk2(f[0], f[1]); tmp.p[1] = pk2(f[2], f[3]);
        VA[s] = tmp.v;
    }
    __syncthreads();

    const int lane = threadIdx.x & 63;
    const int wid = threadIdx.x >> 6;

    for (int qi = wid; qi < 16; qi += 8) {
        int qt = blockIdx.y * 16 + qi;
        if (qt >= 1372) break;                      // wave-uniform
        int tok = qt * 16 + (lane & 15);
        float4 qv = *(const float4*)(P + ((size_t)b * NTOK + tok) * 288
                                     + 96 + h * 16 + (lane >> 4) * 4);
        H4U qb;
        qb.p[0] = pk2(qv.x * SCALE, qv.y * SCALE);
        qb.p[1] = pk2(qv.z * SCALE, qv.w * SCALE);

        f32x4 o; float lsum;
        attn_mfma_core(KA, VA, lane, qb.v, o, lsum);
        lsum += __shfl_xor(lsum, 16);
        lsum += __shfl_xor(lsum, 32);
        float inv = 1.f / (lsum - NPADK);
        float4 out = make_float4(o[0] * inv, o[1] * inv, o[2] * inv, o[3] * inv);
        *(float4*)(y + ((size_t)b * NTOK + tok) * 96 + h * 16 + (lane >> 4) * 4) = out;
    }
}

// ---------------------------------------------------------------------------
// K4: branch-2 windowed attention -> y[:, :, 48:96]   (MFMA)
// ---------------------------------------------------------------------------
__global__ __launch_bounds__(512) void k_attn2(
    const float* __restrict__ P, float* __restrict__ y)
{
    __shared__ h4 KA[NKT * 64];
    __shared__ h4 VA[NKT * 64];
    const int pb = blockIdx.x;
    const int b = pb / 192;
    const int rem = pb % 192;
    const int h = rem / 64, win = rem % 64;
    const int wh = win >> 4, ww = (win >> 2) & 3, wd = win & 3;
    const int h0 = wh * 7, w0 = ww * 7, d0 = wd * 7;
    const size_t bOff = (size_t)b * NTOK;

    for (int s = threadIdx.x; s < NKT * 64; s += 512) {
        int t = s >> 6, l = s & 63;
        int key = t * 16 + (l & 15);
        int dg = (l >> 4) * 4;
        H4U tmp; tmp.p[0] = pk2(0.f, 0.f); tmp.p[1] = pk2(0.f, 0.f);
        if (key < NSR) {
            int a = key / 49, bw = (key / 7) % 7, cw = key % 7;
            int n = (h0 + a) * WD + (w0 + bw) * 28 + (d0 + cw);
            float4 v = *(const float4*)(P + (bOff + n) * 288 + 192 + h * 16 + dg);
            tmp.p[0] = pk2(v.x, v.y); tmp.p[1] = pk2(v.z, v.w);
        }
        KA[s] = tmp.v;
    }
    for (int s = threadIdx.x; s < NKT * 64; s += 512) {
        int t = s >> 6, l = s & 63;
        int dim = l & 15;
        int k0 = t * 16 + (l >> 4) * 4;
        float f[4];
#pragma unroll
        for (int i = 0; i < 4; i++) {
            int key = k0 + i;
            float val = 0.f;
            if (key < NSR) {
                int a = key / 49, bw = (key / 7) % 7, cw = key % 7;
                int n = (h0 + a) * WD + (w0 + bw) * 28 + (d0 + cw);
                val = P[(bOff + n) * 288 + 240 + h * 16 + dim];
            }
            f[i] = val;
        }
        H4U tmp; tmp.p[0] = pk2(f[0], f[1]); tmp.p[1] = pk2(f[2], f[3]);
        VA[s] = tmp.v;
    }
    __syncthreads();

    const int lane = threadIdx.x & 63;
    const int wid = threadIdx.x >> 6;

    for (int qt = wid; qt < NKT; qt += 8) {
        int q = qt * 16 + (lane & 15);
        int qc = (q < NSR) ? q : (NSR - 1);
        int ai = qc / 49, bi = (qc / 7) % 7, ci = qc % 7;
        int tok = (h0 + ai) * WD + (w0 + bi) * 28 + (d0 + ci);
        float4 qv = *(const float4*)(P + (bOff + tok) * 288
                                     + 144 + h * 16 + (lane >> 4) * 4);
        H4U qb;
        qb.p[0] = pk2(qv.x * SCALE, qv.y * SCALE);
        qb.p[1] = pk2(qv.z * SCALE, qv.w * SCALE);

        f32x4 o; float lsum;
        attn_mfma_core(KA, VA, lane, qb.v, o, lsum);
        lsum += __shfl_xor(lsum, 16);
        lsum += __shfl_xor(lsum, 32);
        float inv = 1.f / (lsum - NPADK);
        if (q < NSR) {
            float4 out = make_float4(o[0] * inv, o[1] * inv, o[2] * inv, o[3] * inv);
            *(float4*)(y + (bOff + tok) * 96 + 48 + h * 16 + (lane >> 4) * 4) = out;
        }
    }
}

// ---------------------------------------------------------------------------
// K5: LePE depthwise 3x3x3 conv over t = P[:,0:96]; y += lepe
// ---------------------------------------------------------------------------
__global__ __launch_bounds__(256) void k_lepe(
    const float* __restrict__ P, const float* __restrict__ cwT,
    const float* __restrict__ cb, float* __restrict__ y)
{
    const int p = blockIdx.x;
    const int l = (p & 7) * 515 + (p >> 3);
    if (l >= LNB) return;
    const int id = l * 256 + threadIdx.x;
    const int g4 = (id % 24) * 4;
    const int nl = id / 24;
    const int n = nl % NTOK;
    const int h = n / WD, w = (n / 28) % 28, d = n % 28;
    const float* Pb = P + (size_t)(nl - n) * 288;

    float4 acc = *(const float4*)(cb + g4);
#pragma unroll
    for (int tap = 0; tap < 27; tap++) {
        const int dh = tap / 9 - 1, dw = (tap / 3) % 3 - 1, dd = tap % 3 - 1;
        const int hh = h + dh, ww = w + dw, d2 = d + dd;
        const bool v = ((unsigned)hh < 28u) & ((unsigned)ww < 28u) & ((unsigned)d2 < 28u);
        const int nn = v ? (hh * WD + ww * 28 + d2) : n;
        const float m = v ? 1.f : 0.f;
        float4 pv = *(const float4*)(Pb + (size_t)nn * 288 + g4);
        float4 wv = *(const float4*)(cwT + tap * 96 + g4);
        acc.x += pv.x * (wv.x * m);
        acc.y += pv.y * (wv.y * m);
        acc.z += pv.z * (wv.z * m);
        acc.w += pv.w * (wv.w * m);
    }
    float4* yp = (float4*)(y + (size_t)nl * 96 + g4);
    float4 cur = *yp;
    cur.x += acc.x; cur.y += acc.y; cur.z += acc.z; cur.w += acc.w;
    *yp = cur;
}

// ---------------------------------------------------------------------------
// K6: out = y @ proj_w^T + proj_b  — packed-f16 fdot2 GEMM, 64 tok x 48 j tile
// ---------------------------------------------------------------------------
__global__ __launch_bounds__(192) void k_out(
    const float* __restrict__ y, const float* __restrict__ proj_w,
    const float* __restrict__ proj_b, float* __restrict__ out)
{
    __shared__ h2 xh[48][68];
    __shared__ h2 wh[48][52];

    const int base = blockIdx.x * 64;
    const int j0 = blockIdx.y * 48;

    for (int it = threadIdx.x; it < 1536; it += 192) {
        int t = it & 63, cq = it >> 6;
        float4 v = *(const float4*)(y + (size_t)(base + t) * 96 + cq * 4);
        xh[cq * 2 + 0][t] = pk2(v.x, v.y);
        xh[cq * 2 + 1][t] = pk2(v.z, v.w);
    }
    for (int it = threadIdx.x; it < 1152; it += 192) {
        int jl = it % 48, cq = it / 48;
        float4 v = *(const float4*)(proj_w + (size_t)(j0 + jl) * 96 + cq * 4);
        wh[cq * 2 + 0][jl] = pk2(v.x, v.y);
        wh[cq * 2 + 1][jl] = pk2(v.z, v.w);
    }
    __syncthreads();

    const int tq = threadIdx.x & 15;
    const int jq = threadIdx.x >> 4;
    float acc[4][4];
#pragma unroll
    for (int i = 0; i < 4; i++)
#pragma unroll
        for (int jj = 0; jj < 4; jj++) acc[i][jj] = 0.f;

    for (int cp = 0; cp < 48; cp++) {
        HU xv, wv;
        xv.v = *(const h8*)(&xh[cp][tq * 4]);
        wv.v = *(const h8*)(&wh[cp][jq * 4]);
#pragma unroll
        for (int i = 0; i < 4; i++)
#pragma unroll
            for (int jj = 0; jj < 4; jj++)
                acc[i][jj] = __builtin_amdgcn_fdot2(xv.p[i], wv.p[jj], acc[i][jj], false);
    }

    float4 bias = *(const float4*)(proj_b + j0 + jq * 4);
#pragma unroll
    for (int i = 0; i < 4; i++) {
        int t = base + tq * 4 + i;
        float4 o = make_float4(acc[i][0] + bias.x, acc[i][1] + bias.y,
                               acc[i][2] + bias.z, acc[i][3] + bias.w);
        *(float4*)(out + (size_t)t * 96 + j0 + jq * 4) = o;
    }
}

extern "C" void kernel_launch(void* const* d_in, const int* in_sizes, int n_in,
                              void* d_out, int out_size, void* d_ws, size_t ws_size,
                              hipStream_t stream) {
    const float* x          = (const float*)d_in[0];
    const float* lepe_lin_w = (const float*)d_in[4];
    const float* lepe_lin_b = (const float*)d_in[5];
    const float* lepe_conv_w= (const float*)d_in[6];
    const float* lepe_conv_b= (const float*)d_in[7];
    const float* sr_w       = (const float*)d_in[8];
    const float* sr_b       = (const float*)d_in[9];
    const float* norm_g     = (const float*)d_in[10];
    const float* norm_b     = (const float*)d_in[11];
    const float* q1_w       = (const float*)d_in[12];
    const float* kv1_w      = (const float*)d_in[13];
    const float* q2_w       = (const float*)d_in[14];
    const float* kv2_w      = (const float*)d_in[15];
    const float* proj_w     = (const float*)d_in[16];
    const float* proj_b     = (const float*)d_in[17];

    float* P   = (float*)d_ws;                        // [B*N][288]
    float* k1  = P + (size_t)BB * NTOK * 288;         // [B][3][343][16]
    float* v1  = k1 + (size_t)BB * 3 * NSR * 16;
    float* y   = v1 + (size_t)BB * 3 * NSR * 16;      // [B*N][96]
    float* pa  = y + (size_t)BB * NTOK * 96;          // [686][16][96]
    float* WSAf= pa + (size_t)NSITE * 16 * 96;        // 147456 h4 = 294912 f
    float* WPAf= WSAf + (size_t)WSA_N * 2;            // 6912 h4 = 13824 f
    float* cwT = WPAf + (size_t)WPA_N * 2;            // [27][96]
    h4* WSA = (h4*)WSAf;
    h4* WPA = (h4*)WPAf;

    k_wt<<<614, 256, 0, stream>>>(sr_w, WSA, WPA, lepe_lin_w, q1_w, q2_w,
                                  kv2_w, lepe_conv_w, cwT);
    k_proj<<<686, 256, 0, stream>>>(x, WPA, lepe_lin_b, P);
    k_sr_a<<<dim3(43, 16), 64, 0, stream>>>(x, WSA, pa);
    k_sr_b<<<NSITE, 96, 0, stream>>>(pa, sr_b, norm_g, norm_b, kv1_w, k1, v1);
    k_attn1<<<dim3(6, 86), 512, 0, stream>>>(P, k1, v1, y);
    k_attn2<<<384, 512, 0, stream>>>(P, y);
    k_lepe<<<4120, 256, 0, stream>>>(P, cwT, lepe_conv_b, y);
    k_out<<<dim3(686, 2), 192, 0, stream>>>(y, proj_w, proj_b, (float*)d_out);
}

// Round 8
// 220.384 us; speedup vs baseline: 2.0441x; 1.1717x over previous
//
#include <hip/hip_runtime.h>

#define BB 2
#define NTOK 21952      // 28^3
#define CC 96
#define WD 784          // 28*28
#define NSR 343         // 7^3
#define NKT 22          // key tiles of 16 (352 padded keys)
#define NPADK 9.f       // 352-343 zero-pad keys, each adds exp(0)=1 to lsum
#define NSITE 686       // BB*NSR
#define SCALE 0.25f
#define LN_EPS 1e-5f
#define LNB 4116        // k_lepe logical blocks
#define WSA_N (6*16*24*64)   // 147456 h4 slots: [ct][ks][kt][lane]
#define WPA_N (18*6*64)      // 6912  h4 slots: [ct][kt][lane]

typedef _Float16 half_t;
typedef __attribute__((ext_vector_type(2))) _Float16 h2;
typedef __attribute__((ext_vector_type(4))) _Float16 h4;
typedef __attribute__((ext_vector_type(8))) _Float16 h8;
typedef __attribute__((ext_vector_type(4))) float f32x4;
union HU { h8 v; h2 p[4]; };
union H4U { h4 v; h2 p[2]; };

__device__ __forceinline__ h2 pk2(float a, float b) {
    return __builtin_bit_cast(h2, __builtin_amdgcn_cvt_pkrtz(a, b));
}

// ---------------------------------------------------------------------------
// K0: pack weights into MFMA A-frag layouts.
//   WSA: SR conv weights [co][ci*64+p] -> [ct 6][ks 16][kt 24][lane 64] h4,
//        K ordering k = p*96 + c  (position-major, matches k_sr_a staging).
//   WPA: [lepe|q1|q2|kv2] rows  -> [ct 18][kt 6][lane 64] h4, k = channel.
//   cwT: lepe conv taps transposed [27][96].
// A-frag: lane l = { row co = l&15, k = 4*(l>>4)+i }.
// ---------------------------------------------------------------------------
__global__ __launch_bounds__(256) void k_wt(
    const float* __restrict__ w, h4* __restrict__ WSA, h4* __restrict__ WPA,
    const float* __restrict__ lepe_w, const float* __restrict__ q1_w,
    const float* __restrict__ q2_w, const float* __restrict__ kv2_w,
    const float* __restrict__ cw, float* __restrict__ cwT)
{
    const int id = blockIdx.x * 256 + threadIdx.x;
    if (id < WSA_N) {
        const int lane = id & 63;
        const int kt = (id >> 6) % 24;
        const int ks = ((id >> 6) / 24) % 16;
        const int ct = (id >> 6) / 384;
        const int co = ct * 16 + (lane & 15);
        const int kb = ks * 384 + kt * 16 + 4 * (lane >> 4);
        const int p = kb / 96, c = kb % 96;
        float f[4];
#pragma unroll
        for (int i = 0; i < 4; i++)
            f[i] = w[(size_t)co * 6144 + (c + i) * 64 + p];
        H4U t; t.p[0] = pk2(f[0], f[1]); t.p[1] = pk2(f[2], f[3]);
        WSA[id] = t.v;
    } else if (id < WSA_N + WPA_N) {
        const int id2 = id - WSA_N;
        const int lane = id2 & 63;
        const int kt = (id2 >> 6) % 6;
        const int ct = (id2 >> 6) / 6;
        const int co = ct * 16 + (lane & 15);
        const int k = kt * 16 + 4 * (lane >> 4);
        const float* wrow;
        if (co < 96)       wrow = lepe_w + co * 96;
        else if (co < 144) wrow = q1_w + (co - 96) * 96;
        else if (co < 192) wrow = q2_w + (co - 144) * 96;
        else               wrow = kv2_w + (co - 192) * 96;
        float4 v = *(const float4*)(wrow + k);
        H4U t; t.p[0] = pk2(v.x, v.y); t.p[1] = pk2(v.z, v.w);
        WPA[id2] = t.v;
    } else if (id < WSA_N + WPA_N + 27 * 96) {
        const int id3 = id - WSA_N - WPA_N;
        const int tap = id3 / 96, c = id3 % 96;
        cwT[tap * 96 + c] = cw[c * 27 + tap];
    }
}

// ---------------------------------------------------------------------------
// K1: P[token][288] = x @ [lepe_lin | q1 | q2 | kv2]^T (+ lepe bias on 0:96)
// MFMA: block = 64 tokens, ALL 288 outputs (x fetched exactly once).
// ---------------------------------------------------------------------------
__global__ __launch_bounds__(256) void k_proj(
    const float* __restrict__ x, const h4* __restrict__ WPA,
    const float* __restrict__ lepe_b, float* __restrict__ P)
{
    __shared__ h4 BX[4 * 6 * 64];    // [tt][kt][lane]
    const int blk = blockIdx.x;
    const int tid = threadIdx.x;

    for (int s = tid; s < 1536; s += 256) {
        int lane = s & 63;
        int kt = (s >> 6) % 6;
        int tt = (s >> 6) / 6;
        int tok = blk * 64 + tt * 16 + (lane & 15);
        int k0 = kt * 16 + 4 * (lane >> 4);
        float4 v = *(const float4*)(x + (size_t)tok * 96 + k0);
        H4U t; t.p[0] = pk2(v.x, v.y); t.p[1] = pk2(v.z, v.w);
        BX[s] = t.v;
    }
    __syncthreads();

    const int lane = tid & 63;
    const int wid = tid >> 6;

    h4 bx[24];
#pragma unroll
    for (int q = 0; q < 24; q++) bx[q] = BX[q * 64 + lane];

    for (int ct = wid; ct < 18; ct += 4) {
        f32x4 acc[4];
#pragma unroll
        for (int tt = 0; tt < 4; tt++) acc[tt] = (f32x4){0.f, 0.f, 0.f, 0.f};
#pragma unroll
        for (int kt = 0; kt < 6; kt++) {
            h4 wa = WPA[(ct * 6 + kt) * 64 + lane];
#pragma unroll
            for (int tt = 0; tt < 4; tt++)
                acc[tt] = __builtin_amdgcn_mfma_f32_16x16x16f16(
                    wa, bx[tt * 6 + kt], acc[tt], 0, 0, 0);
        }
        float4 b4 = make_float4(0.f, 0.f, 0.f, 0.f);
        if (ct < 6) b4 = *(const float4*)(lepe_b + ct * 16 + 4 * (lane >> 4));
#pragma unroll
        for (int tt = 0; tt < 4; tt++) {
            int tok = blk * 64 + tt * 16 + (lane & 15);
            float4 o = make_float4(acc[tt][0] + b4.x, acc[tt][1] + b4.y,
                                   acc[tt][2] + b4.z, acc[tt][3] + b4.w);
            *(float4*)(P + (size_t)tok * 288 + ct * 16 + 4 * (lane >> 4)) = o;
        }
    }
}

// ---------------------------------------------------------------------------
// K2a: SR conv as MFMA GEMM. grid (43 site-tiles x 16 K-splits), 384 thr =
// 6 waves, one wave per output co-tile ct. The patch (B-frags) is staged
// cooperatively ONCE into LDS (12.3 KB, per-lane 8B slots -> conflict-free
// ds_read_b64), shared by all 6 waves -> x fetched 1x, 4128 waves total
// (16/CU) instead of 688 (0.67/SIMD) -- fixes the 98%-stall latency exposure
// measured in R7 (VALUBusy 1.75%, Occupancy 6.6%).
// MFMA chain split into 2 independent 12-deep accumulators.
// ---------------------------------------------------------------------------
__global__ __launch_bounds__(384) void k_sr_a(
    const float* __restrict__ x, const h4* __restrict__ WSA,
    float* __restrict__ pa)
{
    __shared__ h4 BX[24 * 64];
    const int mb = blockIdx.x;       // 0..42
    const int ks = blockIdx.y;       // 0..15
    const int tid = threadIdx.x;
    const int lane = tid & 63;
    const int ct = tid >> 6;         // 0..5

    for (int s = tid; s < 24 * 64; s += 384) {
        int l = s & 63;
        int kt = s >> 6;
        int site = mb * 16 + (l & 15);
        if (site > NSITE - 1) site = NSITE - 1;
        int b = site / NSR, sloc = site % NSR;
        int si = sloc / 49, sj = (sloc / 7) % 7, sk = sloc % 7;
        int kg = ks * 384 + kt * 16 + 4 * (l >> 4);
        int p = kg / 96, c = kg % 96;
        int a = p >> 4, q = (p >> 2) & 3, r = p & 3;
        int n = (4 * si + a) * WD + (4 * sj + q) * 28 + (4 * sk + r);
        float4 v = *(const float4*)(x + ((size_t)b * NTOK + n) * 96 + c);
        H4U t; t.p[0] = pk2(v.x, v.y); t.p[1] = pk2(v.z, v.w);
        BX[s] = t.v;
    }
    __syncthreads();

    const int site_g = mb * 16 + (lane & 15);
    const h4* wb = WSA + (size_t)((ct * 16 + ks) * 24) * 64 + lane;

    f32x4 acc0 = (f32x4){0.f, 0.f, 0.f, 0.f};
    f32x4 acc1 = (f32x4){0.f, 0.f, 0.f, 0.f};
#pragma unroll
    for (int kp = 0; kp < 12; kp++) {
        h4 wa0 = wb[(2 * kp) * 64];
        h4 wa1 = wb[(2 * kp + 1) * 64];
        acc0 = __builtin_amdgcn_mfma_f32_16x16x16f16(
            wa0, BX[(2 * kp) * 64 + lane], acc0, 0, 0, 0);
        acc1 = __builtin_amdgcn_mfma_f32_16x16x16f16(
            wa1, BX[(2 * kp + 1) * 64 + lane], acc1, 0, 0, 0);
    }
    if (site_g < NSITE) {
        *(float4*)(pa + ((size_t)site_g * 16 + ks) * 96 + ct * 16
                   + 4 * (lane >> 4)) =
            make_float4(acc0[0] + acc1[0], acc0[1] + acc1[1],
                        acc0[2] + acc1[2], acc0[3] + acc1[3]);
    }
}

// ---------------------------------------------------------------------------
// K2b: reduce 16 partials + bias + LN + GELU + kv1 -> k1/v1 [B][3][343][16]
// ---------------------------------------------------------------------------
__global__ __launch_bounds__(96) void k_sr_b(
    const float* __restrict__ pa, const float* __restrict__ sr_b,
    const float* __restrict__ norm_g, const float* __restrict__ norm_b,
    const float* __restrict__ kv1_w, float* __restrict__ k1,
    float* __restrict__ v1)
{
    __shared__ float xs_s[96];
    __shared__ float gx[96];
    const int s_g = blockIdx.x;
    const int b = s_g / NSR, s = s_g % NSR;
    const int co = threadIdx.x;

    const float* pp = pa + (size_t)s_g * 16 * 96 + co;
    float acc = sr_b[co];
#pragma unroll
    for (int ks = 0; ks < 16; ks++) acc += pp[ks * 96];
    xs_s[co] = acc;
    __syncthreads();

    float m = 0.f, m2 = 0.f;
    for (int c = 0; c < 96; c++) { float v = xs_s[c]; m += v; m2 += v * v; }
    m *= (1.f / 96.f);
    float var = m2 * (1.f / 96.f) - m * m;
    float t = (acc - m) * rsqrtf(var + LN_EPS) * norm_g[co] + norm_b[co];
    gx[co] = 0.5f * t * (1.f + erff(t * 0.70710678118654752f));
    __syncthreads();

    const float4* w4 = (const float4*)(kv1_w + co * 96);
    const float4* g4 = (const float4*)gx;
    float a2 = 0.f;
#pragma unroll
    for (int c = 0; c < 24; c++) {
        float4 w = w4[c]; float4 g = g4[c];
        a2 += g.x * w.x + g.y * w.y + g.z * w.z + g.w * w.w;
    }
    int pair = co / 48, h = (co % 48) / 16, e = co % 16;
    float* dst = pair ? v1 : k1;
    dst[(((size_t)b * 3 + h) * NSR + s) * 16 + e] = a2;
}

// ---------------------------------------------------------------------------
// MFMA attention core (v_mfma_f32_16x16x16_f16, swapped operands).
// ---------------------------------------------------------------------------
__device__ __forceinline__ void attn_mfma_core(
    const h4* __restrict__ KA, const h4* __restrict__ VA, int lane,
    h4 qb, f32x4& o, float& lsum)
{
    o = (f32x4){0.f, 0.f, 0.f, 0.f};
    lsum = 0.f;
    for (int t = 0; t < NKT; t++) {
        h4 ka = KA[t * 64 + lane];
        f32x4 s = __builtin_amdgcn_mfma_f32_16x16x16f16(
            ka, qb, (f32x4){0.f, 0.f, 0.f, 0.f}, 0, 0, 0);
        float p0 = __expf(s[0]), p1 = __expf(s[1]);
        float p2 = __expf(s[2]), p3 = __expf(s[3]);
        lsum += (p0 + p1) + (p2 + p3);
        H4U pb;
        pb.p[0] = pk2(p0, p1);
        pb.p[1] = pk2(p2, p3);
        h4 va = VA[t * 64 + lane];
        o = __builtin_amdgcn_mfma_f32_16x16x16f16(va, pb.v, o, 0, 0, 0);
    }
}

// ---------------------------------------------------------------------------
// K3: branch-1 SR attention -> y[:, :, 0:48]   (MFMA)
// ---------------------------------------------------------------------------
__global__ __launch_bounds__(512) void k_attn1(
    const float* __restrict__ P, const float* __restrict__ k1,
    const float* __restrict__ v1, float* __restrict__ y)
{
    __shared__ h4 KA[NKT * 64];
    __shared__ h4 VA[NKT * 64];
    const int bh = blockIdx.x;
    const int b = bh / 3, h = bh % 3;
    const float* ksrc = k1 + (size_t)bh * NSR * 16;
    const float* vsrc = v1 + (size_t)bh * NSR * 16;

    for (int s = threadIdx.x; s < NKT * 64; s += 512) {
        int t = s >> 6, l = s & 63;
        int key = t * 16 + (l & 15);
        int dg = (l >> 4) * 4;
        H4U tmp; tmp.p[0] = pk2(0.f, 0.f); tmp.p[1] = pk2(0.f, 0.f);
        if (key < NSR) {
            float4 v = *(const float4*)(ksrc + (size_t)key * 16 + dg);
            tmp.p[0] = pk2(v.x, v.y); tmp.p[1] = pk2(v.z, v.w);
        }
        KA[s] = tmp.v;
    }
    for (int s = threadIdx.x; s < NKT * 64; s += 512) {
        int t = s >> 6, l = s & 63;
        int dim = l & 15;
        int k0 = t * 16 + (l >> 4) * 4;
        float f[4];
#pragma unroll
        for (int i = 0; i < 4; i++) {
            int key = k0 + i;
            f[i] = (key < NSR) ? vsrc[(size_t)key * 16 + dim] : 0.f;
        }
        H4U tmp; tmp.p[0] = pk2(f[0], f[1]); tmp.p[1] = pk2(f[2], f[3]);
        VA[s] = tmp.v;
    }
    __syncthreads();

    const int lane = threadIdx.x & 63;
    const int wid = threadIdx.x >> 6;

    for (int qi = wid; qi < 16; qi += 8) {
        int qt = blockIdx.y * 16 + qi;
        if (qt >= 1372) break;                      // wave-uniform
        int tok = qt * 16 + (lane & 15);
        float4 qv = *(const float4*)(P + ((size_t)b * NTOK + tok) * 288
                                     + 96 + h * 16 + (lane >> 4) * 4);
        H4U qb;
        qb.p[0] = pk2(qv.x * SCALE, qv.y * SCALE);
        qb.p[1] = pk2(qv.z * SCALE, qv.w * SCALE);

        f32x4 o; float lsum;
        attn_mfma_core(KA, VA, lane, qb.v, o, lsum);
        lsum += __shfl_xor(lsum, 16);
        lsum += __shfl_xor(lsum, 32);
        float inv = 1.f / (lsum - NPADK);
        float4 out = make_float4(o[0] * inv, o[1] * inv, o[2] * inv, o[3] * inv);
        *(float4*)(y + ((size_t)b * NTOK + tok) * 96 + h * 16 + (lane >> 4) * 4) = out;
    }
}

// ---------------------------------------------------------------------------
// K4: branch-2 windowed attention -> y[:, :, 48:96]   (MFMA)
// ---------------------------------------------------------------------------
__global__ __launch_bounds__(512) void k_attn2(
    const float* __restrict__ P, float* __restrict__ y)
{
    __shared__ h4 KA[NKT * 64];
    __shared__ h4 VA[NKT * 64];
    const int pb = blockIdx.x;
    const int b = pb / 192;
    const int rem = pb % 192;
    const int h = rem / 64, win = rem % 64;
    const int wh = win >> 4, ww = (win >> 2) & 3, wd = win & 3;
    const int h0 = wh * 7, w0 = ww * 7, d0 = wd * 7;
    const size_t bOff = (size_t)b * NTOK;

    for (int s = threadIdx.x; s < NKT * 64; s += 512) {
        int t = s >> 6, l = s & 63;
        int key = t * 16 + (l & 15);
        int dg = (l >> 4) * 4;
        H4U tmp; tmp.p[0] = pk2(0.f, 0.f); tmp.p[1] = pk2(0.f, 0.f);
        if (key < NSR) {
            int a = key / 49, bw = (key / 7) % 7, cw = key % 7;
            int n = (h0 + a) * WD + (w0 + bw) * 28 + (d0 + cw);
            float4 v = *(const float4*)(P + (bOff + n) * 288 + 192 + h * 16 + dg);
            tmp.p[0] = pk2(v.x, v.y); tmp.p[1] = pk2(v.z, v.w);
        }
        KA[s] = tmp.v;
    }
    for (int s = threadIdx.x; s < NKT * 64; s += 512) {
        int t = s >> 6, l = s & 63;
        int dim = l & 15;
        int k0 = t * 16 + (l >> 4) * 4;
        float f[4];
#pragma unroll
        for (int i = 0; i < 4; i++) {
            int key = k0 + i;
            float val = 0.f;
            if (key < NSR) {
                int a = key / 49, bw = (key / 7) % 7, cw = key % 7;
                int n = (h0 + a) * WD + (w0 + bw) * 28 + (d0 + cw);
                val = P[(bOff + n) * 288 + 240 + h * 16 + dim];
            }
            f[i] = val;
        }
        H4U tmp; tmp.p[0] = pk2(f[0], f[1]); tmp.p[1] = pk2(f[2], f[3]);
        VA[s] = tmp.v;
    }
    __syncthreads();

    const int lane = threadIdx.x & 63;
    const int wid = threadIdx.x >> 6;

    for (int qt = wid; qt < NKT; qt += 8) {
        int q = qt * 16 + (lane & 15);
        int qc = (q < NSR) ? q : (NSR - 1);
        int ai = qc / 49, bi = (qc / 7) % 7, ci = qc % 7;
        int tok = (h0 + ai) * WD + (w0 + bi) * 28 + (d0 + ci);
        float4 qv = *(const float4*)(P + (bOff + tok) * 288
                                     + 144 + h * 16 + (lane >> 4) * 4);
        H4U qb;
        qb.p[0] = pk2(qv.x * SCALE, qv.y * SCALE);
        qb.p[1] = pk2(qv.z * SCALE, qv.w * SCALE);

        f32x4 o; float lsum;
        attn_mfma_core(KA, VA, lane, qb.v, o, lsum);
        lsum += __shfl_xor(lsum, 16);
        lsum += __shfl_xor(lsum, 32);
        float inv = 1.f / (lsum - NPADK);
        if (q < NSR) {
            float4 out = make_float4(o[0] * inv, o[1] * inv, o[2] * inv, o[3] * inv);
            *(float4*)(y + (bOff + tok) * 96 + 48 + h * 16 + (lane >> 4) * 4) = out;
        }
    }
}

// ---------------------------------------------------------------------------
// K5: LePE depthwise 3x3x3 conv over t = P[:,0:96]; y += lepe
// ---------------------------------------------------------------------------
__global__ __launch_bounds__(256) void k_lepe(
    const float* __restrict__ P, const float* __restrict__ cwT,
    const float* __restrict__ cb, float* __restrict__ y)
{
    const int p = blockIdx.x;
    const int l = (p & 7) * 515 + (p >> 3);
    if (l >= LNB) return;
    const int id = l * 256 + threadIdx.x;
    const int g4 = (id % 24) * 4;
    const int nl = id / 24;
    const int n = nl % NTOK;
    const int h = n / WD, w = (n / 28) % 28, d = n % 28;
    const float* Pb = P + (size_t)(nl - n) * 288;

    float4 acc = *(const float4*)(cb + g4);
#pragma unroll
    for (int tap = 0; tap < 27; tap++) {
        const int dh = tap / 9 - 1, dw = (tap / 3) % 3 - 1, dd = tap % 3 - 1;
        const int hh = h + dh, ww = w + dw, d2 = d + dd;
        const bool v = ((unsigned)hh < 28u) & ((unsigned)ww < 28u) & ((unsigned)d2 < 28u);
        const int nn = v ? (hh * WD + ww * 28 + d2) : n;
        const float m = v ? 1.f : 0.f;
        float4 pv = *(const float4*)(Pb + (size_t)nn * 288 + g4);
        float4 wv = *(const float4*)(cwT + tap * 96 + g4);
        acc.x += pv.x * (wv.x * m);
        acc.y += pv.y * (wv.y * m);
        acc.z += pv.z * (wv.z * m);
        acc.w += pv.w * (wv.w * m);
    }
    float4* yp = (float4*)(y + (size_t)nl * 96 + g4);
    float4 cur = *yp;
    cur.x += acc.x; cur.y += acc.y; cur.z += acc.z; cur.w += acc.w;
    *yp = cur;
}

// ---------------------------------------------------------------------------
// K6: out = y @ proj_w^T + proj_b  — packed-f16 fdot2 GEMM, 64 tok x 48 j tile
// ---------------------------------------------------------------------------
__global__ __launch_bounds__(192) void k_out(
    const float* __restrict__ y, const float* __restrict__ proj_w,
    const float* __restrict__ proj_b, float* __restrict__ out)
{
    __shared__ h2 xh[48][68];
    __shared__ h2 wh[48][52];

    const int base = blockIdx.x * 64;
    const int j0 = blockIdx.y * 48;

    for (int it = threadIdx.x; it < 1536; it += 192) {
        int t = it & 63, cq = it >> 6;
        float4 v = *(const float4*)(y + (size_t)(base + t) * 96 + cq * 4);
        xh[cq * 2 + 0][t] = pk2(v.x, v.y);
        xh[cq * 2 + 1][t] = pk2(v.z, v.w);
    }
    for (int it = threadIdx.x; it < 1152; it += 192) {
        int jl = it % 48, cq = it / 48;
        float4 v = *(const float4*)(proj_w + (size_t)(j0 + jl) * 96 + cq * 4);
        wh[cq * 2 + 0][jl] = pk2(v.x, v.y);
        wh[cq * 2 + 1][jl] = pk2(v.z, v.w);
    }
    __syncthreads();

    const int tq = threadIdx.x & 15;
    const int jq = threadIdx.x >> 4;
    float acc[4][4];
#pragma unroll
    for (int i = 0; i < 4; i++)
#pragma unroll
        for (int jj = 0; jj < 4; jj++) acc[i][jj] = 0.f;

    for (int cp = 0; cp < 48; cp++) {
        HU xv, wv;
        xv.v = *(const h8*)(&xh[cp][tq * 4]);
        wv.v = *(const h8*)(&wh[cp][jq * 4]);
#pragma unroll
        for (int i = 0; i < 4; i++)
#pragma unroll
            for (int jj = 0; jj < 4; jj++)
                acc[i][jj] = __builtin_amdgcn_fdot2(xv.p[i], wv.p[jj], acc[i][jj], false);
    }

    float4 bias = *(const float4*)(proj_b + j0 + jq * 4);
#pragma unroll
    for (int i = 0; i < 4; i++) {
        int t = base + tq * 4 + i;
        float4 o = make_float4(acc[i][0] + bias.x, acc[i][1] + bias.y,
                               acc[i][2] + bias.z, acc[i][3] + bias.w);
        *(float4*)(out + (size_t)t * 96 + j0 + jq * 4) = o;
    }
}

extern "C" void kernel_launch(void* const* d_in, const int* in_sizes, int n_in,
                              void* d_out, int out_size, void* d_ws, size_t ws_size,
                              hipStream_t stream) {
    const float* x          = (const float*)d_in[0];
    const float* lepe_lin_w = (const float*)d_in[4];
    const float* lepe_lin_b = (const float*)d_in[5];
    const float* lepe_conv_w= (const float*)d_in[6];
    const float* lepe_conv_b= (const float*)d_in[7];
    const float* sr_w       = (const float*)d_in[8];
    const float* sr_b       = (const float*)d_in[9];
    const float* norm_g     = (const float*)d_in[10];
    const float* norm_b     = (const float*)d_in[11];
    const float* q1_w       = (const float*)d_in[12];
    const float* kv1_w      = (const float*)d_in[13];
    const float* q2_w       = (const float*)d_in[14];
    const float* kv2_w      = (const float*)d_in[15];
    const float* proj_w     = (const float*)d_in[16];
    const float* proj_b     = (const float*)d_in[17];

    float* P   = (float*)d_ws;                        // [B*N][288]
    float* k1  = P + (size_t)BB * NTOK * 288;         // [B][3][343][16]
    float* v1  = k1 + (size_t)BB * 3 * NSR * 16;
    float* y   = v1 + (size_t)BB * 3 * NSR * 16;      // [B*N][96]
    float* pa  = y + (size_t)BB * NTOK * 96;          // [686][16][96]
    float* WSAf= pa + (size_t)NSITE * 16 * 96;        // 147456 h4 = 294912 f
    float* WPAf= WSAf + (size_t)WSA_N * 2;            // 6912 h4 = 13824 f
    float* cwT = WPAf + (size_t)WPA_N * 2;            // [27][96]
    h4* WSA = (h4*)WSAf;
    h4* WPA = (h4*)WPAf;

    k_wt<<<614, 256, 0, stream>>>(sr_w, WSA, WPA, lepe_lin_w, q1_w, q2_w,
                                  kv2_w, lepe_conv_w, cwT);
    k_proj<<<686, 256, 0, stream>>>(x, WPA, lepe_lin_b, P);
    k_sr_a<<<dim3(43, 16), 384, 0, stream>>>(x, WSA, pa);
    k_sr_b<<<NSITE, 96, 0, stream>>>(pa, sr_b, norm_g, norm_b, kv1_w, k1, v1);
    k_attn1<<<dim3(6, 86), 512, 0, stream>>>(P, k1, v1, y);
    k_attn2<<<384, 512, 0, stream>>>(P, y);
    k_lepe<<<4120, 256, 0, stream>>>(P, cwT, lepe_conv_b, y);
    k_out<<<dim3(686, 2), 192, 0, stream>>>(y, proj_w, proj_b, (float*)d_out);
}

// Round 9
// 218.914 us; speedup vs baseline: 2.0578x; 1.0067x over previous
//
#include <hip/hip_runtime.h>

#define BB 2
#define NTOK 21952      // 28^3
#define CC 96
#define WD 784          // 28*28
#define NSR 343         // 7^3
#define NKT 22          // key tiles of 16 (352 padded keys)
#define NPADK 9.f       // 352-343 zero-pad keys, each adds exp(0)=1 to lsum
#define NSITE 686       // BB*NSR
#define SCALE 0.25f
#define LN_EPS 1e-5f
#define WSA_N (6*16*24*64)   // 147456 h4 slots: [ct][ks][kt][lane]
#define WPA_N (18*6*64)      // 6912  h4 slots: [ct][kt][lane]

typedef _Float16 half_t;
typedef __attribute__((ext_vector_type(2))) _Float16 h2;
typedef __attribute__((ext_vector_type(4))) _Float16 h4;
typedef __attribute__((ext_vector_type(8))) _Float16 h8;
typedef __attribute__((ext_vector_type(4))) float f32x4;
union HU { h8 v; h2 p[4]; };
union H4U { h4 v; h2 p[2]; };

__device__ __forceinline__ h2 pk2(float a, float b) {
    return __builtin_bit_cast(h2, __builtin_amdgcn_cvt_pkrtz(a, b));
}

// ---------------------------------------------------------------------------
// K0: pack weights into MFMA A-frag layouts.
//   WSA: SR conv weights [co][ci*64+p] -> [ct 6][ks 16][kt 24][lane 64] h4,
//        K ordering k = p*96 + c  (position-major, matches k_sr_a staging).
//   WPA: [lepe|q1|q2|kv2] rows  -> [ct 18][kt 6][lane 64] h4, k = channel.
//   cwT: lepe conv taps transposed [27][96].
// A-frag: lane l = { row co = l&15, k = 4*(l>>4)+i }.
// ---------------------------------------------------------------------------
__global__ __launch_bounds__(256) void k_wt(
    const float* __restrict__ w, h4* __restrict__ WSA, h4* __restrict__ WPA,
    const float* __restrict__ lepe_w, const float* __restrict__ q1_w,
    const float* __restrict__ q2_w, const float* __restrict__ kv2_w,
    const float* __restrict__ cw, float* __restrict__ cwT)
{
    const int id = blockIdx.x * 256 + threadIdx.x;
    if (id < WSA_N) {
        const int lane = id & 63;
        const int kt = (id >> 6) % 24;
        const int ks = ((id >> 6) / 24) % 16;
        const int ct = (id >> 6) / 384;
        const int co = ct * 16 + (lane & 15);
        const int kb = ks * 384 + kt * 16 + 4 * (lane >> 4);
        const int p = kb / 96, c = kb % 96;
        float f[4];
#pragma unroll
        for (int i = 0; i < 4; i++)
            f[i] = w[(size_t)co * 6144 + (c + i) * 64 + p];
        H4U t; t.p[0] = pk2(f[0], f[1]); t.p[1] = pk2(f[2], f[3]);
        WSA[id] = t.v;
    } else if (id < WSA_N + WPA_N) {
        const int id2 = id - WSA_N;
        const int lane = id2 & 63;
        const int kt = (id2 >> 6) % 6;
        const int ct = (id2 >> 6) / 6;
        const int co = ct * 16 + (lane & 15);
        const int k = kt * 16 + 4 * (lane >> 4);
        const float* wrow;
        if (co < 96)       wrow = lepe_w + co * 96;
        else if (co < 144) wrow = q1_w + (co - 96) * 96;
        else if (co < 192) wrow = q2_w + (co - 144) * 96;
        else               wrow = kv2_w + (co - 192) * 96;
        float4 v = *(const float4*)(wrow + k);
        H4U t; t.p[0] = pk2(v.x, v.y); t.p[1] = pk2(v.z, v.w);
        WPA[id2] = t.v;
    } else if (id < WSA_N + WPA_N + 27 * 96) {
        const int id3 = id - WSA_N - WPA_N;
        const int tap = id3 / 96, c = id3 % 96;
        cwT[tap * 96 + c] = cw[c * 27 + tap];
    }
}

// ---------------------------------------------------------------------------
// K1: P[token][288] = x @ [lepe_lin | q1 | q2 | kv2]^T (+ lepe bias on 0:96)
// MFMA: block = 64 tokens, ALL 288 outputs (x fetched exactly once).
// ---------------------------------------------------------------------------
__global__ __launch_bounds__(256) void k_proj(
    const float* __restrict__ x, const h4* __restrict__ WPA,
    const float* __restrict__ lepe_b, float* __restrict__ P)
{
    __shared__ h4 BX[4 * 6 * 64];    // [tt][kt][lane]
    const int blk = blockIdx.x;
    const int tid = threadIdx.x;

    for (int s = tid; s < 1536; s += 256) {
        int lane = s & 63;
        int kt = (s >> 6) % 6;
        int tt = (s >> 6) / 6;
        int tok = blk * 64 + tt * 16 + (lane & 15);
        int k0 = kt * 16 + 4 * (lane >> 4);
        float4 v = *(const float4*)(x + (size_t)tok * 96 + k0);
        H4U t; t.p[0] = pk2(v.x, v.y); t.p[1] = pk2(v.z, v.w);
        BX[s] = t.v;
    }
    __syncthreads();

    const int lane = tid & 63;
    const int wid = tid >> 6;

    h4 bx[24];
#pragma unroll
    for (int q = 0; q < 24; q++) bx[q] = BX[q * 64 + lane];

    for (int ct = wid; ct < 18; ct += 4) {
        f32x4 acc[4];
#pragma unroll
        for (int tt = 0; tt < 4; tt++) acc[tt] = (f32x4){0.f, 0.f, 0.f, 0.f};
#pragma unroll
        for (int kt = 0; kt < 6; kt++) {
            h4 wa = WPA[(ct * 6 + kt) * 64 + lane];
#pragma unroll
            for (int tt = 0; tt < 4; tt++)
                acc[tt] = __builtin_amdgcn_mfma_f32_16x16x16f16(
                    wa, bx[tt * 6 + kt], acc[tt], 0, 0, 0);
        }
        float4 b4 = make_float4(0.f, 0.f, 0.f, 0.f);
        if (ct < 6) b4 = *(const float4*)(lepe_b + ct * 16 + 4 * (lane >> 4));
#pragma unroll
        for (int tt = 0; tt < 4; tt++) {
            int tok = blk * 64 + tt * 16 + (lane & 15);
            float4 o = make_float4(acc[tt][0] + b4.x, acc[tt][1] + b4.y,
                                   acc[tt][2] + b4.z, acc[tt][3] + b4.w);
            *(float4*)(P + (size_t)tok * 288 + ct * 16 + 4 * (lane >> 4)) = o;
        }
    }
}

// ---------------------------------------------------------------------------
// K2a: SR conv as MFMA GEMM. grid (43 site-tiles x 16 K-splits), 384 thr =
// 6 waves, one wave per output co-tile ct. Patch staged once into LDS,
// shared by all 6 waves (16 waves/CU occupancy).
// ---------------------------------------------------------------------------
__global__ __launch_bounds__(384) void k_sr_a(
    const float* __restrict__ x, const h4* __restrict__ WSA,
    float* __restrict__ pa)
{
    __shared__ h4 BX[24 * 64];
    const int mb = blockIdx.x;       // 0..42
    const int ks = blockIdx.y;       // 0..15
    const int tid = threadIdx.x;
    const int lane = tid & 63;
    const int ct = tid >> 6;         // 0..5

    for (int s = tid; s < 24 * 64; s += 384) {
        int l = s & 63;
        int kt = s >> 6;
        int site = mb * 16 + (l & 15);
        if (site > NSITE - 1) site = NSITE - 1;
        int b = site / NSR, sloc = site % NSR;
        int si = sloc / 49, sj = (sloc / 7) % 7, sk = sloc % 7;
        int kg = ks * 384 + kt * 16 + 4 * (l >> 4);
        int p = kg / 96, c = kg % 96;
        int a = p >> 4, q = (p >> 2) & 3, r = p & 3;
        int n = (4 * si + a) * WD + (4 * sj + q) * 28 + (4 * sk + r);
        float4 v = *(const float4*)(x + ((size_t)b * NTOK + n) * 96 + c);
        H4U t; t.p[0] = pk2(v.x, v.y); t.p[1] = pk2(v.z, v.w);
        BX[s] = t.v;
    }
    __syncthreads();

    const int site_g = mb * 16 + (lane & 15);
    const h4* wb = WSA + (size_t)((ct * 16 + ks) * 24) * 64 + lane;

    f32x4 acc0 = (f32x4){0.f, 0.f, 0.f, 0.f};
    f32x4 acc1 = (f32x4){0.f, 0.f, 0.f, 0.f};
#pragma unroll
    for (int kp = 0; kp < 12; kp++) {
        h4 wa0 = wb[(2 * kp) * 64];
        h4 wa1 = wb[(2 * kp + 1) * 64];
        acc0 = __builtin_amdgcn_mfma_f32_16x16x16f16(
            wa0, BX[(2 * kp) * 64 + lane], acc0, 0, 0, 0);
        acc1 = __builtin_amdgcn_mfma_f32_16x16x16f16(
            wa1, BX[(2 * kp + 1) * 64 + lane], acc1, 0, 0, 0);
    }
    if (site_g < NSITE) {
        *(float4*)(pa + ((size_t)site_g * 16 + ks) * 96 + ct * 16
                   + 4 * (lane >> 4)) =
            make_float4(acc0[0] + acc1[0], acc0[1] + acc1[1],
                        acc0[2] + acc1[2], acc0[3] + acc1[3]);
    }
}

// ---------------------------------------------------------------------------
// K2b: reduce 16 partials + bias + LN + GELU + kv1 -> k1/v1 [B][3][343][16]
// ---------------------------------------------------------------------------
__global__ __launch_bounds__(96) void k_sr_b(
    const float* __restrict__ pa, const float* __restrict__ sr_b,
    const float* __restrict__ norm_g, const float* __restrict__ norm_b,
    const float* __restrict__ kv1_w, float* __restrict__ k1,
    float* __restrict__ v1)
{
    __shared__ float xs_s[96];
    __shared__ float gx[96];
    const int s_g = blockIdx.x;
    const int b = s_g / NSR, s = s_g % NSR;
    const int co = threadIdx.x;

    const float* pp = pa + (size_t)s_g * 16 * 96 + co;
    float acc = sr_b[co];
#pragma unroll
    for (int ks = 0; ks < 16; ks++) acc += pp[ks * 96];
    xs_s[co] = acc;
    __syncthreads();

    float m = 0.f, m2 = 0.f;
    for (int c = 0; c < 96; c++) { float v = xs_s[c]; m += v; m2 += v * v; }
    m *= (1.f / 96.f);
    float var = m2 * (1.f / 96.f) - m * m;
    float t = (acc - m) * rsqrtf(var + LN_EPS) * norm_g[co] + norm_b[co];
    gx[co] = 0.5f * t * (1.f + erff(t * 0.70710678118654752f));
    __syncthreads();

    const float4* w4 = (const float4*)(kv1_w + co * 96);
    const float4* g4 = (const float4*)gx;
    float a2 = 0.f;
#pragma unroll
    for (int c = 0; c < 24; c++) {
        float4 w = w4[c]; float4 g = g4[c];
        a2 += g.x * w.x + g.y * w.y + g.z * w.z + g.w * w.w;
    }
    int pair = co / 48, h = (co % 48) / 16, e = co % 16;
    float* dst = pair ? v1 : k1;
    dst[(((size_t)b * 3 + h) * NSR + s) * 16 + e] = a2;
}

// ---------------------------------------------------------------------------
// MFMA attention core (v_mfma_f32_16x16x16_f16, swapped operands).
// ---------------------------------------------------------------------------
__device__ __forceinline__ void attn_mfma_core(
    const h4* __restrict__ KA, const h4* __restrict__ VA, int lane,
    h4 qb, f32x4& o, float& lsum)
{
    o = (f32x4){0.f, 0.f, 0.f, 0.f};
    lsum = 0.f;
    for (int t = 0; t < NKT; t++) {
        h4 ka = KA[t * 64 + lane];
        f32x4 s = __builtin_amdgcn_mfma_f32_16x16x16f16(
            ka, qb, (f32x4){0.f, 0.f, 0.f, 0.f}, 0, 0, 0);
        float p0 = __expf(s[0]), p1 = __expf(s[1]);
        float p2 = __expf(s[2]), p3 = __expf(s[3]);
        lsum += (p0 + p1) + (p2 + p3);
        H4U pb;
        pb.p[0] = pk2(p0, p1);
        pb.p[1] = pk2(p2, p3);
        h4 va = VA[t * 64 + lane];
        o = __builtin_amdgcn_mfma_f32_16x16x16f16(va, pb.v, o, 0, 0, 0);
    }
}

// ---------------------------------------------------------------------------
// K3: branch-1 SR attention -> y[:, :, 0:48]   (MFMA)
// ---------------------------------------------------------------------------
__global__ __launch_bounds__(512) void k_attn1(
    const float* __restrict__ P, const float* __restrict__ k1,
    const float* __restrict__ v1, float* __restrict__ y)
{
    __shared__ h4 KA[NKT * 64];
    __shared__ h4 VA[NKT * 64];
    const int bh = blockIdx.x;
    const int b = bh / 3, h = bh % 3;
    const float* ksrc = k1 + (size_t)bh * NSR * 16;
    const float* vsrc = v1 + (size_t)bh * NSR * 16;

    for (int s = threadIdx.x; s < NKT * 64; s += 512) {
        int t = s >> 6, l = s & 63;
        int key = t * 16 + (l & 15);
        int dg = (l >> 4) * 4;
        H4U tmp; tmp.p[0] = pk2(0.f, 0.f); tmp.p[1] = pk2(0.f, 0.f);
        if (key < NSR) {
            float4 v = *(const float4*)(ksrc + (size_t)key * 16 + dg);
            tmp.p[0] = pk2(v.x, v.y); tmp.p[1] = pk2(v.z, v.w);
        }
        KA[s] = tmp.v;
    }
    for (int s = threadIdx.x; s < NKT * 64; s += 512) {
        int t = s >> 6, l = s & 63;
        int dim = l & 15;
        int k0 = t * 16 + (l >> 4) * 4;
        float f[4];
#pragma unroll
        for (int i = 0; i < 4; i++) {
            int key = k0 + i;
            f[i] = (key < NSR) ? vsrc[(size_t)key * 16 + dim] : 0.f;
        }
        H4U tmp; tmp.p[0] = pk2(f[0], f[1]); tmp.p[1] = pk2(f[2], f[3]);
        VA[s] = tmp.v;
    }
    __syncthreads();

    const int lane = threadIdx.x & 63;
    const int wid = threadIdx.x >> 6;

    for (int qi = wid; qi < 16; qi += 8) {
        int qt = blockIdx.y * 16 + qi;
        if (qt >= 1372) break;                      // wave-uniform
        int tok = qt * 16 + (lane & 15);
        float4 qv = *(const float4*)(P + ((size_t)b * NTOK + tok) * 288
                                     + 96 + h * 16 + (lane >> 4) * 4);
        H4U qb;
        qb.p[0] = pk2(qv.x * SCALE, qv.y * SCALE);
        qb.p[1] = pk2(qv.z * SCALE, qv.w * SCALE);

        f32x4 o; float lsum;
        attn_mfma_core(KA, VA, lane, qb.v, o, lsum);
        lsum += __shfl_xor(lsum, 16);
        lsum += __shfl_xor(lsum, 32);
        float inv = 1.f / (lsum - NPADK);
        float4 out = make_float4(o[0] * inv, o[1] * inv, o[2] * inv, o[3] * inv);
        *(float4*)(y + ((size_t)b * NTOK + tok) * 96 + h * 16 + (lane >> 4) * 4) = out;
    }
}

// ---------------------------------------------------------------------------
// K4: branch-2 windowed attention -> y[:, :, 48:96]   (MFMA)
// ---------------------------------------------------------------------------
__global__ __launch_bounds__(512) void k_attn2(
    const float* __restrict__ P, float* __restrict__ y)
{
    __shared__ h4 KA[NKT * 64];
    __shared__ h4 VA[NKT * 64];
    const int pb = blockIdx.x;
    const int b = pb / 192;
    const int rem = pb % 192;
    const int h = rem / 64, win = rem % 64;
    const int wh = win >> 4, ww = (win >> 2) & 3, wd = win & 3;
    const int h0 = wh * 7, w0 = ww * 7, d0 = wd * 7;
    const size_t bOff = (size_t)b * NTOK;

    for (int s = threadIdx.x; s < NKT * 64; s += 512) {
        int t = s >> 6, l = s & 63;
        int key = t * 16 + (l & 15);
        int dg = (l >> 4) * 4;
        H4U tmp; tmp.p[0] = pk2(0.f, 0.f); tmp.p[1] = pk2(0.f, 0.f);
        if (key < NSR) {
            int a = key / 49, bw = (key / 7) % 7, cw = key % 7;
            int n = (h0 + a) * WD + (w0 + bw) * 28 + (d0 + cw);
            float4 v = *(const float4*)(P + (bOff + n) * 288 + 192 + h * 16 + dg);
            tmp.p[0] = pk2(v.x, v.y); tmp.p[1] = pk2(v.z, v.w);
        }
        KA[s] = tmp.v;
    }
    for (int s = threadIdx.x; s < NKT * 64; s += 512) {
        int t = s >> 6, l = s & 63;
        int dim = l & 15;
        int k0 = t * 16 + (l >> 4) * 4;
        float f[4];
#pragma unroll
        for (int i = 0; i < 4; i++) {
            int key = k0 + i;
            float val = 0.f;
            if (key < NSR) {
                int a = key / 49, bw = (key / 7) % 7, cw = key % 7;
                int n = (h0 + a) * WD + (w0 + bw) * 28 + (d0 + cw);
                val = P[(bOff + n) * 288 + 240 + h * 16 + dim];
            }
            f[i] = val;
        }
        H4U tmp; tmp.p[0] = pk2(f[0], f[1]); tmp.p[1] = pk2(f[2], f[3]);
        VA[s] = tmp.v;
    }
    __syncthreads();

    const int lane = threadIdx.x & 63;
    const int wid = threadIdx.x >> 6;

    for (int qt = wid; qt < NKT; qt += 8) {
        int q = qt * 16 + (lane & 15);
        int qc = (q < NSR) ? q : (NSR - 1);
        int ai = qc / 49, bi = (qc / 7) % 7, ci = qc % 7;
        int tok = (h0 + ai) * WD + (w0 + bi) * 28 + (d0 + ci);
        float4 qv = *(const float4*)(P + (bOff + tok) * 288
                                     + 144 + h * 16 + (lane >> 4) * 4);
        H4U qb;
        qb.p[0] = pk2(qv.x * SCALE, qv.y * SCALE);
        qb.p[1] = pk2(qv.z * SCALE, qv.w * SCALE);

        f32x4 o; float lsum;
        attn_mfma_core(KA, VA, lane, qb.v, o, lsum);
        lsum += __shfl_xor(lsum, 16);
        lsum += __shfl_xor(lsum, 32);
        float inv = 1.f / (lsum - NPADK);
        if (q < NSR) {
            float4 out = make_float4(o[0] * inv, o[1] * inv, o[2] * inv, o[3] * inv);
            *(float4*)(y + (bOff + tok) * 96 + 48 + h * 16 + (lane >> 4) * 4) = out;
        }
    }
}

// ---------------------------------------------------------------------------
// K5: LePE depthwise 3x3x3 conv over t = P[:,0:96]; y += lepe
// Register d-blocking: one thread computes 7 consecutive d-outputs. Per
// (dh,dw) the 9-position d-window is loaded once (pv[9]) and each element
// feeds 3 outputs -> loads/output 28 -> 12.6 (2.2x). Plane mask folded into
// the 3 weight regs; d mask zeroes window loads. Grid 588x256 exact.
// ---------------------------------------------------------------------------
__global__ __launch_bounds__(256) void k_lepe(
    const float* __restrict__ P, const float* __restrict__ cwT,
    const float* __restrict__ cb, float* __restrict__ y)
{
    const int id = blockIdx.x * 256 + threadIdx.x;   // 150528 total
    const int g4 = (id % 24) * 4;
    const int rest = id / 24;
    const int dc = rest % 4;
    const int nw = rest / 4;             // b*784 + h*28 + w
    const int w = nw % 28;
    const int h = (nw / 28) % 28;
    const int b = nw / 784;
    const int d0 = dc * 7;
    const float* Pb = P + (size_t)b * NTOK * 288;

    float4 bias = *(const float4*)(cb + g4);
    float4 acc[7];
#pragma unroll
    for (int j = 0; j < 7; j++) acc[j] = bias;

#pragma unroll
    for (int dh = -1; dh <= 1; dh++) {
#pragma unroll
        for (int dw = -1; dw <= 1; dw++) {
            const int hh = h + dh, ww = w + dw;
            const bool pok = ((unsigned)hh < 28u) & ((unsigned)ww < 28u);
            const int nbase = (pok ? hh : h) * WD + (pok ? ww : w) * 28;
            const float mp = pok ? 1.f : 0.f;
            const int tb = ((dh + 1) * 3 + (dw + 1)) * 3;
            float4 wm = *(const float4*)(cwT + (tb + 0) * 96 + g4);
            float4 w0 = *(const float4*)(cwT + (tb + 1) * 96 + g4);
            float4 wp = *(const float4*)(cwT + (tb + 2) * 96 + g4);
            wm.x *= mp; wm.y *= mp; wm.z *= mp; wm.w *= mp;
            w0.x *= mp; w0.y *= mp; w0.z *= mp; w0.w *= mp;
            wp.x *= mp; wp.y *= mp; wp.z *= mp; wp.w *= mp;

            float4 pv[9];
#pragma unroll
            for (int k = 0; k < 9; k++) {
                const int d = d0 + k - 1;
                const bool dok = (unsigned)d < 28u;
                float4 v = *(const float4*)(Pb + (size_t)(nbase + (dok ? d : 0)) * 288 + g4);
                if (!dok) v = make_float4(0.f, 0.f, 0.f, 0.f);
                pv[k] = v;
            }
#pragma unroll
            for (int j = 0; j < 7; j++) {
                acc[j].x += pv[j].x * wm.x + pv[j + 1].x * w0.x + pv[j + 2].x * wp.x;
                acc[j].y += pv[j].y * wm.y + pv[j + 1].y * w0.y + pv[j + 2].y * wp.y;
                acc[j].z += pv[j].z * wm.z + pv[j + 1].z * w0.z + pv[j + 2].z * wp.z;
                acc[j].w += pv[j].w * wm.w + pv[j + 1].w * w0.w + pv[j + 2].w * wp.w;
            }
        }
    }

    const size_t tokBase = (size_t)b * NTOK + h * WD + w * 28 + d0;
#pragma unroll
    for (int j = 0; j < 7; j++) {
        float4* yp = (float4*)(y + (tokBase + j) * 96 + g4);
        float4 cur = *yp;
        cur.x += acc[j].x; cur.y += acc[j].y;
        cur.z += acc[j].z; cur.w += acc[j].w;
        *yp = cur;
    }
}

// ---------------------------------------------------------------------------
// K6: out = y @ proj_w^T + proj_b  — packed-f16 fdot2 GEMM, 64 tok x 48 j tile
// ---------------------------------------------------------------------------
__global__ __launch_bounds__(192) void k_out(
    const float* __restrict__ y, const float* __restrict__ proj_w,
    const float* __restrict__ proj_b, float* __restrict__ out)
{
    __shared__ h2 xh[48][68];
    __shared__ h2 wh[48][52];

    const int base = blockIdx.x * 64;
    const int j0 = blockIdx.y * 48;

    for (int it = threadIdx.x; it < 1536; it += 192) {
        int t = it & 63, cq = it >> 6;
        float4 v = *(const float4*)(y + (size_t)(base + t) * 96 + cq * 4);
        xh[cq * 2 + 0][t] = pk2(v.x, v.y);
        xh[cq * 2 + 1][t] = pk2(v.z, v.w);
    }
    for (int it = threadIdx.x; it < 1152; it += 192) {
        int jl = it % 48, cq = it / 48;
        float4 v = *(const float4*)(proj_w + (size_t)(j0 + jl) * 96 + cq * 4);
        wh[cq * 2 + 0][jl] = pk2(v.x, v.y);
        wh[cq * 2 + 1][jl] = pk2(v.z, v.w);
    }
    __syncthreads();

    const int tq = threadIdx.x & 15;
    const int jq = threadIdx.x >> 4;
    float acc[4][4];
#pragma unroll
    for (int i = 0; i < 4; i++)
#pragma unroll
        for (int jj = 0; jj < 4; jj++) acc[i][jj] = 0.f;

    for (int cp = 0; cp < 48; cp++) {
        HU xv, wv;
        xv.v = *(const h8*)(&xh[cp][tq * 4]);
        wv.v = *(const h8*)(&wh[cp][jq * 4]);
#pragma unroll
        for (int i = 0; i < 4; i++)
#pragma unroll
            for (int jj = 0; jj < 4; jj++)
                acc[i][jj] = __builtin_amdgcn_fdot2(xv.p[i], wv.p[jj], acc[i][jj], false);
    }

    float4 bias = *(const float4*)(proj_b + j0 + jq * 4);
#pragma unroll
    for (int i = 0; i < 4; i++) {
        int t = base + tq * 4 + i;
        float4 o = make_float4(acc[i][0] + bias.x, acc[i][1] + bias.y,
                               acc[i][2] + bias.z, acc[i][3] + bias.w);
        *(float4*)(out + (size_t)t * 96 + j0 + jq * 4) = o;
    }
}

extern "C" void kernel_launch(void* const* d_in, const int* in_sizes, int n_in,
                              void* d_out, int out_size, void* d_ws, size_t ws_size,
                              hipStream_t stream) {
    const float* x          = (const float*)d_in[0];
    const float* lepe_lin_w = (const float*)d_in[4];
    const float* lepe_lin_b = (const float*)d_in[5];
    const float* lepe_conv_w= (const float*)d_in[6];
    const float* lepe_conv_b= (const float*)d_in[7];
    const float* sr_w       = (const float*)d_in[8];
    const float* sr_b       = (const float*)d_in[9];
    const float* norm_g     = (const float*)d_in[10];
    const float* norm_b     = (const float*)d_in[11];
    const float* q1_w       = (const float*)d_in[12];
    const float* kv1_w      = (const float*)d_in[13];
    const float* q2_w       = (const float*)d_in[14];
    const float* kv2_w      = (const float*)d_in[15];
    const float* proj_w     = (const float*)d_in[16];
    const float* proj_b     = (const float*)d_in[17];

    float* P   = (float*)d_ws;                        // [B*N][288]
    float* k1  = P + (size_t)BB * NTOK * 288;         // [B][3][343][16]
    float* v1  = k1 + (size_t)BB * 3 * NSR * 16;
    float* y   = v1 + (size_t)BB * 3 * NSR * 16;      // [B*N][96]
    float* pa  = y + (size_t)BB * NTOK * 96;          // [686][16][96]
    float* WSAf= pa + (size_t)NSITE * 16 * 96;        // 147456 h4 = 294912 f
    float* WPAf= WSAf + (size_t)WSA_N * 2;            // 6912 h4 = 13824 f
    float* cwT = WPAf + (size_t)WPA_N * 2;            // [27][96]
    h4* WSA = (h4*)WSAf;
    h4* WPA = (h4*)WPAf;

    k_wt<<<614, 256, 0, stream>>>(sr_w, WSA, WPA, lepe_lin_w, q1_w, q2_w,
                                  kv2_w, lepe_conv_w, cwT);
    k_proj<<<686, 256, 0, stream>>>(x, WPA, lepe_lin_b, P);
    k_sr_a<<<dim3(43, 16), 384, 0, stream>>>(x, WSA, pa);
    k_sr_b<<<NSITE, 96, 0, stream>>>(pa, sr_b, norm_g, norm_b, kv1_w, k1, v1);
    k_attn1<<<dim3(6, 86), 512, 0, stream>>>(P, k1, v1, y);
    k_attn2<<<384, 512, 0, stream>>>(P, y);
    k_lepe<<<588, 256, 0, stream>>>(P, cwT, lepe_conv_b, y);
    k_out<<<dim3(686, 2), 192, 0, stream>>>(y, proj_w, proj_b, (float*)d_out);
}